// Round 1
// baseline (17258.249 us; speedup 1.0000x reference)
//
#include <hip/hip_runtime.h>

#define DEV_INLINE __device__ __forceinline__

DEV_INLINE int dot4(int a, int b, int c) {
#if __has_builtin(__builtin_amdgcn_sdot4)
    return __builtin_amdgcn_sdot4(a, b, c, false);
#else
    return c
        + (int)(signed char)(a)       * (int)(signed char)(b)
        + (int)(signed char)(a >> 8)  * (int)(signed char)(b >> 8)
        + (int)(signed char)(a >> 16) * (int)(signed char)(b >> 16)
        + (int)(signed char)(a >> 24) * (int)(signed char)(b >> 24);
#endif
}

// ---------------- conversion kernels ----------------

// OIHW fp32 -> [O][KK][Ipad] int8 (pad input channels with zeros)
__global__ void cvt_w_conv(const float* __restrict__ w, signed char* __restrict__ o,
                           int O, int I, int KK, int Ipad) {
    int idx = blockIdx.x * blockDim.x + threadIdx.x;
    int total = O * KK * Ipad;
    if (idx >= total) return;
    int i = idx % Ipad;
    int t = idx / Ipad;
    int kk = t % KK;
    int oc = t / KK;
    float v = (i < I) ? w[(oc * I + i) * KK + kk] : 0.0f;
    o[idx] = (signed char)(int)v;
}

__global__ void cvt_i8(const float* __restrict__ w, signed char* __restrict__ o, int n) {
    int idx = blockIdx.x * blockDim.x + threadIdx.x;
    if (idx < n) o[idx] = (signed char)(int)w[idx];
}

__global__ void cvt_i32(const float* __restrict__ b, int* __restrict__ o, int n) {
    int idx = blockIdx.x * blockDim.x + threadIdx.x;
    if (idx < n) o[idx] = (int)b[idx];
}

// ---------------- quantize input: NCHW fp32 [512,3,32,32] -> NHWC int8 [512,32,32,4] ----------------

__global__ void quantize_in(const float* __restrict__ x, signed char* __restrict__ q, int total) {
    int idx = blockIdx.x * blockDim.x + threadIdx.x;
    if (idx >= total) return;                 // total = 512*32*32
    int hw = idx & 1023;
    int n = idx >> 10;
    const float* xp = x + n * 3072 + hw;
    int b[4];
#pragma unroll
    for (int c = 0; c < 3; ++c) {
        float v = rintf(xp[c * 1024] / 0.05f);
        v = fminf(fmaxf(v, -128.0f), 127.0f);
        b[c] = (int)v;
    }
    b[3] = 0;
    int packed = (b[0] & 0xff) | ((b[1] & 0xff) << 8) | ((b[2] & 0xff) << 16) | (b[3] << 24);
    ((int*)q)[idx] = packed;
}

// ---------------- direct conv, NHWC int8, 8 oc per thread ----------------

template <int K>
__global__ void qconv(const signed char* __restrict__ act,
                      const signed char* __restrict__ wq,
                      const int* __restrict__ bias,
                      signed char* __restrict__ out,
                      int N, int H, int W, int Cin,
                      int OH, int OW, int Cout, int pad, float M) {
    int site = blockIdx.x * blockDim.x + threadIdx.x;
    int total = N * OH * OW;
    if (site >= total) return;
    int ox = site % OW;
    int t = site / OW;
    int oy = t % OH;
    int n = t / OH;
    int ocb = blockIdx.y * 8;

    int acc[8];
#pragma unroll
    for (int j = 0; j < 8; ++j) acc[j] = bias[ocb + j];

    int c4 = Cin >> 2;
    int wstride = (K * K * Cin) >> 2;   // ints per output channel
    const int* actI = (const int*)act;
    const int* wI = (const int*)wq;

    for (int ky = 0; ky < K; ++ky) {
        int iy = oy - pad + ky;
        if ((unsigned)iy >= (unsigned)H) continue;
        for (int kx = 0; kx < K; ++kx) {
            int ix = ox - pad + kx;
            if ((unsigned)ix >= (unsigned)W) continue;
            const int* ap = actI + ((((n * H + iy) * W + ix) * Cin) >> 2);
            const int* wp = wI + ((((ocb * K + ky) * K + kx) * Cin) >> 2);
            for (int i = 0; i < c4; ++i) {
                int a = ap[i];
#pragma unroll
                for (int j = 0; j < 8; ++j)
                    acc[j] = dot4(a, wp[j * wstride + i], acc[j]);
            }
        }
    }

    signed char* op = out + (size_t)site * Cout + ocb;
#pragma unroll
    for (int j = 0; j < 8; ++j) {
        float v = floorf((float)acc[j] * M);
        v = fminf(fmaxf(v, 0.0f), 127.0f);
        op[j] = (signed char)v;
    }
}

// ---------------- maxpool 3x3 stride 2, NHWC, 4 channels per thread ----------------

__global__ void qmaxpool(const signed char* __restrict__ in, signed char* __restrict__ out,
                         int N, int H, int W, int C4, int OH, int OW) {
    int idx = blockIdx.x * blockDim.x + threadIdx.x;
    int total = N * OH * OW * C4;
    if (idx >= total) return;
    int cc = idx % C4;
    int t = idx / C4;
    int ox = t % OW; t /= OW;
    int oy = t % OH;
    int n = t / OH;
    const int* ip = (const int*)in;
    int base = ((n * H + oy * 2) * W + ox * 2) * C4 + cc;
    int m0 = -128, m1 = -128, m2 = -128, m3 = -128;
#pragma unroll
    for (int dy = 0; dy < 3; ++dy)
#pragma unroll
        for (int dx = 0; dx < 3; ++dx) {
            int v = ip[base + (dy * W + dx) * C4];
            m0 = max(m0, (int)(signed char)(v & 0xff));
            m1 = max(m1, (int)(signed char)((v >> 8) & 0xff));
            m2 = max(m2, (int)(signed char)((v >> 16) & 0xff));
            m3 = max(m3, (int)(signed char)(v >> 24));
        }
    ((int*)out)[idx] = (m0 & 0xff) | ((m1 & 0xff) << 8) | ((m2 & 0xff) << 16) | (m3 << 24);
}

// ---------------- global avg pool over 3x3 + floor: [512,3,3,256] -> [512,256] ----------------

__global__ void qgap(const signed char* __restrict__ in, signed char* __restrict__ out) {
    int idx = blockIdx.x * blockDim.x + threadIdx.x;
    if (idx >= 512 * 256) return;
    int c = idx & 255;
    int n = idx >> 8;
    const signed char* p = in + n * 9 * 256 + c;
    int s = 0;
#pragma unroll
    for (int k = 0; k < 9; ++k) s += p[k * 256];
    out[idx] = (signed char)(s / 9);   // values >= 0, so this is floor(mean)
}

// ---------------- FC with relu: 8 batch x 8 out per thread ----------------

__global__ void qfc(const signed char* __restrict__ act,
                    const signed char* __restrict__ wq,
                    const int* __restrict__ bias,
                    signed char* __restrict__ out,
                    int B, int K, int O, float M) {
    int idx = blockIdx.x * blockDim.x + threadIdx.x;
    int og_n = O >> 3;
    int total = (B >> 3) * og_n;
    if (idx >= total) return;
    int og = idx % og_n;
    int bg = idx / og_n;
    int b0 = bg << 3, o0 = og << 3;
    int k4 = K >> 2;

    int acc[8][8];
#pragma unroll
    for (int i = 0; i < 8; ++i)
#pragma unroll
        for (int j = 0; j < 8; ++j) acc[i][j] = bias[o0 + j];

    const int* aI = (const int*)act;
    const int* wI = (const int*)wq;
    for (int k = 0; k < k4; ++k) {
        int a[8], w[8];
#pragma unroll
        for (int i = 0; i < 8; ++i) a[i] = aI[(b0 + i) * k4 + k];
#pragma unroll
        for (int j = 0; j < 8; ++j) w[j] = wI[(o0 + j) * k4 + k];
#pragma unroll
        for (int i = 0; i < 8; ++i)
#pragma unroll
            for (int j = 0; j < 8; ++j)
                acc[i][j] = dot4(a[i], w[j], acc[i][j]);
    }

#pragma unroll
    for (int i = 0; i < 8; ++i)
#pragma unroll
        for (int j = 0; j < 8; ++j) {
            float v = floorf((float)acc[i][j] * M);
            v = fminf(fmaxf(v, 0.0f), 127.0f);
            out[(b0 + i) * O + o0 + j] = (signed char)v;
        }
}

// ---------------- final FC (no relu), fp32 output ----------------

__global__ void qfc3(const signed char* __restrict__ act,
                     const signed char* __restrict__ wq,
                     const int* __restrict__ bias,
                     float* __restrict__ out,
                     int B, int K, int O, float M) {
    int idx = blockIdx.x * blockDim.x + threadIdx.x;
    if (idx >= B * O) return;
    int o = idx % O;
    int b = idx / O;
    int k4 = K >> 2;
    int acc = bias[o];
    const int* aI = (const int*)act + b * k4;
    const int* wI = (const int*)wq + o * k4;
    for (int k = 0; k < k4; ++k) acc = dot4(aI[k], wI[k], acc);
    float v = floorf((float)acc * M);
    v = fminf(fmaxf(v, -128.0f), 127.0f);
    out[idx] = v;
}

// ---------------- launch ----------------

#define LAUNCH(kern, n, ...) kern<<<dim3(((n) + 255) / 256), dim3(256), 0, stream>>>(__VA_ARGS__)

extern "C" void kernel_launch(void* const* d_in, const int* in_sizes, int n_in,
                              void* d_out, int out_size, void* d_ws, size_t ws_size,
                              hipStream_t stream) {
    const float* x   = (const float*)d_in[0];
    const float* w1  = (const float*)d_in[1];
    const float* b1  = (const float*)d_in[2];
    const float* w2  = (const float*)d_in[3];
    const float* b2  = (const float*)d_in[4];
    const float* w3  = (const float*)d_in[5];
    const float* b3  = (const float*)d_in[6];
    const float* w4  = (const float*)d_in[7];
    const float* b4  = (const float*)d_in[8];
    const float* w5  = (const float*)d_in[9];
    const float* b5  = (const float*)d_in[10];
    const float* wf1 = (const float*)d_in[11];
    const float* bf1 = (const float*)d_in[12];
    const float* wf2 = (const float*)d_in[13];
    const float* bf2 = (const float*)d_in[14];
    const float* wf3 = (const float*)d_in[15];
    const float* bf3 = (const float*)d_in[16];
    float* out = (float*)d_out;

    char* ws = (char*)d_ws;
    size_t off = 0;
    auto A = [&](size_t sz) -> size_t {
        size_t o = off;
        off += (sz + 255) & ~(size_t)255;
        return o;
    };

    size_t wq1  = A(96 * 25 * 4);
    size_t wq2  = A(256 * 25 * 96);
    size_t wq3  = A(384 * 9 * 256);
    size_t wq4  = A(384 * 9 * 384);
    size_t wq5  = A(256 * 9 * 384);
    size_t wqf1 = A(4096 * 256);
    size_t wqf2 = A((size_t)4096 * 4096);
    size_t wqf3 = A(10 * 4096);
    size_t bq1  = A(96 * 4);
    size_t bq2  = A(256 * 4);
    size_t bq3  = A(384 * 4);
    size_t bq4  = A(384 * 4);
    size_t bq5  = A(256 * 4);
    size_t bqf1 = A(4096 * 4);
    size_t bqf2 = A(4096 * 4);
    size_t bqf3 = A(10 * 4);
    size_t bufA = A(11059200);   // max: pool1 out [512,15,15,96]
    size_t bufB = A(50331648);   // max: conv1 out [512,32,32,96]
    if (off > ws_size) return;   // workspace too small — bail rather than corrupt

    signed char* W1 = (signed char*)(ws + wq1);
    signed char* W2 = (signed char*)(ws + wq2);
    signed char* W3 = (signed char*)(ws + wq3);
    signed char* W4 = (signed char*)(ws + wq4);
    signed char* W5 = (signed char*)(ws + wq5);
    signed char* WF1 = (signed char*)(ws + wqf1);
    signed char* WF2 = (signed char*)(ws + wqf2);
    signed char* WF3 = (signed char*)(ws + wqf3);
    int* B1 = (int*)(ws + bq1);
    int* B2 = (int*)(ws + bq2);
    int* B3 = (int*)(ws + bq3);
    int* B4 = (int*)(ws + bq4);
    int* B5 = (int*)(ws + bq5);
    int* BF1 = (int*)(ws + bqf1);
    int* BF2 = (int*)(ws + bqf2);
    int* BF3 = (int*)(ws + bqf3);
    signed char* A_ = (signed char*)(ws + bufA);
    signed char* Bb = (signed char*)(ws + bufB);

    // ---- weight/bias conversion ----
    LAUNCH(cvt_w_conv, 96 * 25 * 4, w1, W1, 96, 3, 25, 4);
    LAUNCH(cvt_w_conv, 256 * 25 * 96, w2, W2, 256, 96, 25, 96);
    LAUNCH(cvt_w_conv, 384 * 9 * 256, w3, W3, 384, 256, 9, 256);
    LAUNCH(cvt_w_conv, 384 * 9 * 384, w4, W4, 384, 384, 9, 384);
    LAUNCH(cvt_w_conv, 256 * 9 * 384, w5, W5, 256, 384, 9, 384);
    LAUNCH(cvt_i8, 4096 * 256, wf1, WF1, 4096 * 256);
    LAUNCH(cvt_i8, 4096 * 4096, wf2, WF2, 4096 * 4096);
    LAUNCH(cvt_i8, 10 * 4096, wf3, WF3, 10 * 4096);
    LAUNCH(cvt_i32, 96, b1, B1, 96);
    LAUNCH(cvt_i32, 256, b2, B2, 256);
    LAUNCH(cvt_i32, 384, b3, B3, 384);
    LAUNCH(cvt_i32, 384, b4, B4, 384);
    LAUNCH(cvt_i32, 256, b5, B5, 256);
    LAUNCH(cvt_i32, 4096, bf1, BF1, 4096);
    LAUNCH(cvt_i32, 4096, bf2, BF2, 4096);
    LAUNCH(cvt_i32, 10, bf3, BF3, 10);

    // ---- forward ----
    // quantize: x -> A_ [512,32,32,4]
    LAUNCH(quantize_in, 512 * 1024, x, A_, 512 * 1024);

    // conv1: A_ -> Bb [512,32,32,96]
    {
        int sites = 512 * 32 * 32;
        qconv<5><<<dim3((sites + 255) / 256, 96 / 8), dim3(256), 0, stream>>>(
            A_, W1, B1, Bb, 512, 32, 32, 4, 32, 32, 96, 2, 2e-3f);
    }
    // pool1: Bb -> A_ [512,15,15,96]
    LAUNCH(qmaxpool, 512 * 15 * 15 * 24, Bb, A_, 512, 32, 32, 24, 15, 15);
    // conv2: A_ -> Bb [512,15,15,256]
    {
        int sites = 512 * 15 * 15;
        qconv<5><<<dim3((sites + 255) / 256, 256 / 8), dim3(256), 0, stream>>>(
            A_, W2, B2, Bb, 512, 15, 15, 96, 15, 15, 256, 2, 4e-4f);
    }
    // pool2: Bb -> A_ [512,7,7,256]
    LAUNCH(qmaxpool, 512 * 7 * 7 * 64, Bb, A_, 512, 15, 15, 64, 7, 7);
    // conv3: A_ -> Bb [512,7,7,384]
    {
        int sites = 512 * 7 * 7;
        qconv<3><<<dim3((sites + 255) / 256, 384 / 8), dim3(256), 0, stream>>>(
            A_, W3, B3, Bb, 512, 7, 7, 256, 7, 7, 384, 1, 2e-4f);
    }
    // conv4: Bb -> A_ [512,7,7,384]
    {
        int sites = 512 * 7 * 7;
        qconv<3><<<dim3((sites + 255) / 256, 384 / 8), dim3(256), 0, stream>>>(
            Bb, W4, B4, A_, 512, 7, 7, 384, 7, 7, 384, 1, 2e-4f);
    }
    // conv5: A_ -> Bb [512,7,7,256]
    {
        int sites = 512 * 7 * 7;
        qconv<3><<<dim3((sites + 255) / 256, 256 / 8), dim3(256), 0, stream>>>(
            A_, W5, B5, Bb, 512, 7, 7, 384, 7, 7, 256, 1, 2e-4f);
    }
    // pool3: Bb -> A_ [512,3,3,256]
    LAUNCH(qmaxpool, 512 * 3 * 3 * 64, Bb, A_, 512, 7, 7, 64, 3, 3);
    // gap: A_ -> Bb [512,256]
    LAUNCH(qgap, 512 * 256, A_, Bb);
    // fc1: Bb -> A_ [512,4096]
    LAUNCH(qfc, (512 / 8) * (4096 / 8), Bb, WF1, BF1, A_, 512, 256, 4096, 1e-3f);
    // fc2: A_ -> Bb [512,4096]
    LAUNCH(qfc, (512 / 8) * (4096 / 8), A_, WF2, BF2, Bb, 512, 4096, 4096, 2e-4f);
    // fc3: Bb -> out [512,10] fp32
    LAUNCH(qfc3, 512 * 10, Bb, WF3, BF3, out, 512, 4096, 10, 2e-4f);
}

// Round 2
// 3091.910 us; speedup vs baseline: 5.5817x; 5.5817x over previous
//
#include <hip/hip_runtime.h>

#define DEV_INLINE __device__ __forceinline__

typedef int i32x4 __attribute__((ext_vector_type(4)));

DEV_INLINE int dot4(int a, int b, int c) {
#if __has_builtin(__builtin_amdgcn_sdot4)
    return __builtin_amdgcn_sdot4(a, b, c, false);
#else
    return c
        + (int)(signed char)(a)       * (int)(signed char)(b)
        + (int)(signed char)(a >> 8)  * (int)(signed char)(b >> 8)
        + (int)(signed char)(a >> 16) * (int)(signed char)(b >> 16)
        + (int)(signed char)(a >> 24) * (int)(signed char)(b >> 24);
#endif
}

// ---------------- conversion kernels ----------------

// OIHW fp32 -> [O][KK][Ipad] int8 (pad input channels with zeros)
__global__ void cvt_w_conv(const float* __restrict__ w, signed char* __restrict__ o,
                           int O, int I, int KK, int Ipad) {
    int idx = blockIdx.x * blockDim.x + threadIdx.x;
    int total = O * KK * Ipad;
    if (idx >= total) return;
    int i = idx % Ipad;
    int t = idx / Ipad;
    int kk = t % KK;
    int oc = t / KK;
    float v = (i < I) ? w[(oc * I + i) * KK + kk] : 0.0f;
    o[idx] = (signed char)(int)v;
}

__global__ void cvt_i8(const float* __restrict__ w, signed char* __restrict__ o, int n) {
    int idx = blockIdx.x * blockDim.x + threadIdx.x;
    if (idx < n) o[idx] = (signed char)(int)w[idx];
}

__global__ void cvt_i32(const float* __restrict__ b, int* __restrict__ o, int n) {
    int idx = blockIdx.x * blockDim.x + threadIdx.x;
    if (idx < n) o[idx] = (int)b[idx];
}

// ---------------- quantize input: NCHW fp32 [512,3,32,32] -> NHWC int8 [512,32,32,4] ----------------

__global__ void quantize_in(const float* __restrict__ x, signed char* __restrict__ q, int total) {
    int idx = blockIdx.x * blockDim.x + threadIdx.x;
    if (idx >= total) return;                 // total = 512*32*32
    int hw = idx & 1023;
    int n = idx >> 10;
    const float* xp = x + n * 3072 + hw;
    int b[4];
#pragma unroll
    for (int c = 0; c < 3; ++c) {
        float v = rintf(xp[c * 1024] / 0.05f);
        v = fminf(fmaxf(v, -128.0f), 127.0f);
        b[c] = (int)v;
    }
    b[3] = 0;
    int packed = (b[0] & 0xff) | ((b[1] & 0xff) << 8) | ((b[2] & 0xff) << 16) | (b[3] << 24);
    ((int*)q)[idx] = packed;
}

// ---------------- conv1 direct: Cin=4, K=5, Cout=96. 16 oc/thread, 6 threads/site ----------------

__global__ void qconv1(const signed char* __restrict__ act,
                       const signed char* __restrict__ wq,
                       const int* __restrict__ bias,
                       signed char* __restrict__ out, int total) {
    int t = blockIdx.x * blockDim.x + threadIdx.x;
    if (t >= total) return;                       // total = 512*32*32*6
    int ocg = t % 6;
    int site = t / 6;
    int ox = site & 31;
    int oy = (site >> 5) & 31;
    int n = site >> 10;

    int acc[16];
    const int* bp = bias + ocg * 16;
#pragma unroll
    for (int j = 0; j < 16; ++j) acc[j] = bp[j];

    const int* aI = (const int*)act;              // [512,32,32] ints (4ch packed)
    const int* wI = (const int*)wq;               // [96][25] ints
    const int* wg = wI + ocg * 16 * 25;

#pragma unroll
    for (int ky = 0; ky < 5; ++ky) {
        int iy = oy - 2 + ky;
        if ((unsigned)iy >= 32u) continue;
#pragma unroll
        for (int kx = 0; kx < 5; ++kx) {
            int ix = ox - 2 + kx;
            if ((unsigned)ix >= 32u) continue;
            int a = aI[(n << 10) + (iy << 5) + ix];
            const int* wp = wg + (ky * 5 + kx);
#pragma unroll
            for (int j = 0; j < 16; ++j)
                acc[j] = dot4(a, wp[j * 25], acc[j]);
        }
    }

    int packed[4];
#pragma unroll
    for (int w = 0; w < 4; ++w) {
        int b4[4];
#pragma unroll
        for (int s = 0; s < 4; ++s) {
            float v = floorf((float)acc[w * 4 + s] * 2e-3f);
            v = fminf(fmaxf(v, 0.0f), 127.0f);
            b4[s] = (int)v;
        }
        packed[w] = (b4[0] & 0xff) | ((b4[1] & 0xff) << 8) | ((b4[2] & 0xff) << 16) | (b4[3] << 24);
    }
    i32x4 p = {packed[0], packed[1], packed[2], packed[3]};
    *(i32x4*)(out + (size_t)t * 16) = p;          // lane-contiguous 16B -> full-line writes
}

// ---------------- implicit-GEMM MFMA conv (also FC with KS=1) ----------------
// act: NHWC int8 (Cin multiple of 16), wq: [Cout][KS*KS*Cin] int8, out: NHWC int8
// Wave tile: 16 sites x 64 oc. Block: 4 waves -> 64 sites x 64 oc.
// grid.x = M/64 (M = N*OH*OW, multiple of 64), grid.y = Cout/64.

template <int KS, int CIN>
__global__ void conv_mfma(const signed char* __restrict__ act,
                          const signed char* __restrict__ wq,
                          const int* __restrict__ bias,
                          signed char* __restrict__ out,
                          int H, int W, int OH, int OW, int Cout, int pad, float M) {
    constexpr int C16 = CIN / 16;                 // 16-byte chunks per tap
    constexpr int K16 = KS * KS * C16;            // total 16-chunks in K
    constexpr int KSTEPS = (K16 + 3) / 4;         // 64-wide MFMA K-steps
    constexpr int KROW = KS * KS * CIN;           // weight row bytes

    int lane = threadIdx.x & 63;
    int wid = threadIdx.x >> 6;
    int siteBase = blockIdx.x * 64 + wid * 16;
    int oc0 = blockIdx.y * 64;

    int mA = lane & 15;                           // A row within tile
    int q = lane >> 4;                            // k-chunk sub-index (0..3)

    // A-side site (fixed per lane)
    int siteA = siteBase + mA;
    int ox = siteA % OW;
    int t = siteA / OW;
    int oy = t % OH;
    int n = t / OH;
    const size_t rowBase = (size_t)n * H;         // in rows

    // D-side oc (fixed per lane)
    int ocD = oc0 + (lane & 15);

    i32x4 acc[4];
#pragma unroll
    for (int j = 0; j < 4; ++j) {
        int bv = bias[ocD + 16 * j];
        acc[j] = (i32x4){bv, bv, bv, bv};
    }

    // weight chunk base per jtile: row (ocD+16j), chunk offset q*16; advances 64 B/step
    const signed char* wp[4];
#pragma unroll
    for (int j = 0; j < 4; ++j)
        wp[j] = wq + (size_t)(ocD + 16 * j) * KROW + q * 16;

    for (int step = 0; step < KSTEPS; ++step) {
        int k16 = step * 4 + q;
        int tap = k16 / C16;                      // const-div -> magic mul
        int c16 = k16 - tap * C16;
        int iy = oy - pad + tap / KS;
        int ix = ox - pad + tap % KS;
        bool kok = (k16 < K16);
        bool aok = kok && ((unsigned)iy < (unsigned)H) && ((unsigned)ix < (unsigned)W);

        i32x4 a = (i32x4){0, 0, 0, 0};
        if (aok)
            a = *(const i32x4*)(act + (((rowBase + iy) * W + ix) * CIN + c16 * 16));

#pragma unroll
        for (int j = 0; j < 4; ++j) {
            i32x4 b = (i32x4){0, 0, 0, 0};
            if (kok) b = *(const i32x4*)(wp[j] + (size_t)step * 64);
            acc[j] = __builtin_amdgcn_mfma_i32_16x16x64_i8(a, b, acc[j], 0, 0, 0);
        }
    }

    // D layout: row = (lane>>4)*4 + reg, col = lane&15 (+16j)
    int q4 = q * 4;
#pragma unroll
    for (int j = 0; j < 4; ++j) {
        int oc = ocD + 16 * j;
#pragma unroll
        for (int r = 0; r < 4; ++r) {
            int site = siteBase + q4 + r;
            float v = floorf((float)acc[j][r] * M);
            v = fminf(fmaxf(v, 0.0f), 127.0f);
            out[(size_t)site * Cout + oc] = (signed char)v;
        }
    }
}

// ---------------- maxpool 3x3 stride 2, NHWC, 4 channels per thread ----------------

__global__ void qmaxpool(const signed char* __restrict__ in, signed char* __restrict__ out,
                         int N, int H, int W, int C4, int OH, int OW) {
    int idx = blockIdx.x * blockDim.x + threadIdx.x;
    int total = N * OH * OW * C4;
    if (idx >= total) return;
    int cc = idx % C4;
    int t = idx / C4;
    int ox = t % OW; t /= OW;
    int oy = t % OH;
    int n = t / OH;
    const int* ip = (const int*)in;
    int base = ((n * H + oy * 2) * W + ox * 2) * C4 + cc;
    int m0 = -128, m1 = -128, m2 = -128, m3 = -128;
#pragma unroll
    for (int dy = 0; dy < 3; ++dy)
#pragma unroll
        for (int dx = 0; dx < 3; ++dx) {
            int v = ip[base + (dy * W + dx) * C4];
            m0 = max(m0, (int)(signed char)(v & 0xff));
            m1 = max(m1, (int)(signed char)((v >> 8) & 0xff));
            m2 = max(m2, (int)(signed char)((v >> 16) & 0xff));
            m3 = max(m3, (int)(signed char)(v >> 24));
        }
    ((int*)out)[idx] = (m0 & 0xff) | ((m1 & 0xff) << 8) | ((m2 & 0xff) << 16) | (m3 << 24);
}

// ---------------- global avg pool over 3x3 + floor: [512,3,3,256] -> [512,256] ----------------

__global__ void qgap(const signed char* __restrict__ in, signed char* __restrict__ out) {
    int idx = blockIdx.x * blockDim.x + threadIdx.x;
    if (idx >= 512 * 256) return;
    int c = idx & 255;
    int n = idx >> 8;
    const signed char* p = in + n * 9 * 256 + c;
    int s = 0;
#pragma unroll
    for (int k = 0; k < 9; ++k) s += p[k * 256];
    out[idx] = (signed char)(s / 9);   // values >= 0, so this is floor(mean)
}

// ---------------- final FC (no relu), fp32 output ----------------

__global__ void qfc3(const signed char* __restrict__ act,
                     const signed char* __restrict__ wq,
                     const int* __restrict__ bias,
                     float* __restrict__ out,
                     int B, int K, int O, float M) {
    int idx = blockIdx.x * blockDim.x + threadIdx.x;
    if (idx >= B * O) return;
    int o = idx % O;
    int b = idx / O;
    int k4 = K >> 2;
    int acc = bias[o];
    const int* aI = (const int*)act + b * k4;
    const int* wI = (const int*)wq + o * k4;
    for (int k = 0; k < k4; ++k) acc = dot4(aI[k], wI[k], acc);
    float v = floorf((float)acc * M);
    v = fminf(fmaxf(v, -128.0f), 127.0f);
    out[idx] = v;
}

// ---------------- launch ----------------

#define LAUNCH(kern, n, ...) kern<<<dim3(((n) + 255) / 256), dim3(256), 0, stream>>>(__VA_ARGS__)

extern "C" void kernel_launch(void* const* d_in, const int* in_sizes, int n_in,
                              void* d_out, int out_size, void* d_ws, size_t ws_size,
                              hipStream_t stream) {
    const float* x   = (const float*)d_in[0];
    const float* w1  = (const float*)d_in[1];
    const float* b1  = (const float*)d_in[2];
    const float* w2  = (const float*)d_in[3];
    const float* b2  = (const float*)d_in[4];
    const float* w3  = (const float*)d_in[5];
    const float* b3  = (const float*)d_in[6];
    const float* w4  = (const float*)d_in[7];
    const float* b4  = (const float*)d_in[8];
    const float* w5  = (const float*)d_in[9];
    const float* b5  = (const float*)d_in[10];
    const float* wf1 = (const float*)d_in[11];
    const float* bf1 = (const float*)d_in[12];
    const float* wf2 = (const float*)d_in[13];
    const float* bf2 = (const float*)d_in[14];
    const float* wf3 = (const float*)d_in[15];
    const float* bf3 = (const float*)d_in[16];
    float* out = (float*)d_out;

    char* ws = (char*)d_ws;
    size_t off = 0;
    auto A = [&](size_t sz) -> size_t {
        size_t o = off;
        off += (sz + 255) & ~(size_t)255;
        return o;
    };

    size_t wq1  = A(96 * 25 * 4);
    size_t wq2  = A(256 * 25 * 96);
    size_t wq3  = A(384 * 9 * 256);
    size_t wq4  = A(384 * 9 * 384);
    size_t wq5  = A(256 * 9 * 384);
    size_t wqf1 = A(4096 * 256);
    size_t wqf2 = A((size_t)4096 * 4096);
    size_t wqf3 = A(10 * 4096);
    size_t bq1  = A(96 * 4);
    size_t bq2  = A(256 * 4);
    size_t bq3  = A(384 * 4);
    size_t bq4  = A(384 * 4);
    size_t bq5  = A(256 * 4);
    size_t bqf1 = A(4096 * 4);
    size_t bqf2 = A(4096 * 4);
    size_t bqf3 = A(10 * 4);
    size_t bufA = A(11059200);   // max: pool1 out [512,15,15,96]
    size_t bufB = A(50331648);   // max: conv1 out [512,32,32,96]
    if (off > ws_size) return;   // workspace too small — bail rather than corrupt

    signed char* W1 = (signed char*)(ws + wq1);
    signed char* W2 = (signed char*)(ws + wq2);
    signed char* W3 = (signed char*)(ws + wq3);
    signed char* W4 = (signed char*)(ws + wq4);
    signed char* W5 = (signed char*)(ws + wq5);
    signed char* WF1 = (signed char*)(ws + wqf1);
    signed char* WF2 = (signed char*)(ws + wqf2);
    signed char* WF3 = (signed char*)(ws + wqf3);
    int* B1 = (int*)(ws + bq1);
    int* B2 = (int*)(ws + bq2);
    int* B3 = (int*)(ws + bq3);
    int* B4 = (int*)(ws + bq4);
    int* B5 = (int*)(ws + bq5);
    int* BF1 = (int*)(ws + bqf1);
    int* BF2 = (int*)(ws + bqf2);
    int* BF3 = (int*)(ws + bqf3);
    signed char* A_ = (signed char*)(ws + bufA);
    signed char* Bb = (signed char*)(ws + bufB);

    // ---- weight/bias conversion ----
    LAUNCH(cvt_w_conv, 96 * 25 * 4, w1, W1, 96, 3, 25, 4);
    LAUNCH(cvt_w_conv, 256 * 25 * 96, w2, W2, 256, 96, 25, 96);
    LAUNCH(cvt_w_conv, 384 * 9 * 256, w3, W3, 384, 256, 9, 256);
    LAUNCH(cvt_w_conv, 384 * 9 * 384, w4, W4, 384, 384, 9, 384);
    LAUNCH(cvt_w_conv, 256 * 9 * 384, w5, W5, 256, 384, 9, 384);
    LAUNCH(cvt_i8, 4096 * 256, wf1, WF1, 4096 * 256);
    LAUNCH(cvt_i8, 4096 * 4096, wf2, WF2, 4096 * 4096);
    LAUNCH(cvt_i8, 10 * 4096, wf3, WF3, 10 * 4096);
    LAUNCH(cvt_i32, 96, b1, B1, 96);
    LAUNCH(cvt_i32, 256, b2, B2, 256);
    LAUNCH(cvt_i32, 384, b3, B3, 384);
    LAUNCH(cvt_i32, 384, b4, B4, 384);
    LAUNCH(cvt_i32, 256, b5, B5, 256);
    LAUNCH(cvt_i32, 4096, bf1, BF1, 4096);
    LAUNCH(cvt_i32, 4096, bf2, BF2, 4096);
    LAUNCH(cvt_i32, 10, bf3, BF3, 10);

    // ---- forward ----
    // quantize: x -> A_ [512,32,32,4]
    LAUNCH(quantize_in, 512 * 1024, x, A_, 512 * 1024);

    // conv1 (direct): A_ -> Bb [512,32,32,96]
    LAUNCH(qconv1, 512 * 32 * 32 * 6, A_, W1, B1, Bb, 512 * 32 * 32 * 6);

    // pool1: Bb -> A_ [512,15,15,96]
    LAUNCH(qmaxpool, 512 * 15 * 15 * 24, Bb, A_, 512, 32, 32, 24, 15, 15);

    // conv2 (MFMA): A_ -> Bb [512,15,15,256]; M = 512*225 = 115200
    conv_mfma<5, 96><<<dim3(115200 / 64, 256 / 64), dim3(256), 0, stream>>>(
        A_, W2, B2, Bb, 15, 15, 15, 15, 256, 2, 4e-4f);

    // pool2: Bb -> A_ [512,7,7,256]
    LAUNCH(qmaxpool, 512 * 7 * 7 * 64, Bb, A_, 512, 15, 15, 64, 7, 7);

    // conv3 (MFMA): A_ -> Bb [512,7,7,384]; M = 25088
    conv_mfma<3, 256><<<dim3(25088 / 64, 384 / 64), dim3(256), 0, stream>>>(
        A_, W3, B3, Bb, 7, 7, 7, 7, 384, 1, 2e-4f);

    // conv4 (MFMA): Bb -> A_ [512,7,7,384]
    conv_mfma<3, 384><<<dim3(25088 / 64, 384 / 64), dim3(256), 0, stream>>>(
        Bb, W4, B4, A_, 7, 7, 7, 7, 384, 1, 2e-4f);

    // conv5 (MFMA): A_ -> Bb [512,7,7,256]
    conv_mfma<3, 384><<<dim3(25088 / 64, 256 / 64), dim3(256), 0, stream>>>(
        A_, W5, B5, Bb, 7, 7, 7, 7, 256, 1, 2e-4f);

    // pool3: Bb -> A_ [512,3,3,256]
    LAUNCH(qmaxpool, 512 * 3 * 3 * 64, Bb, A_, 512, 7, 7, 64, 3, 3);

    // gap: A_ -> Bb [512,256]
    LAUNCH(qgap, 512 * 256, A_, Bb);

    // fc1 (MFMA as KS=1 conv): Bb -> A_ [512,4096]
    conv_mfma<1, 256><<<dim3(512 / 64, 4096 / 64), dim3(256), 0, stream>>>(
        Bb, WF1, BF1, A_, 1, 1, 1, 1, 4096, 0, 1e-3f);

    // fc2 (MFMA): A_ -> Bb [512,4096]
    conv_mfma<1, 4096><<<dim3(512 / 64, 4096 / 64), dim3(256), 0, stream>>>(
        A_, WF2, BF2, Bb, 1, 1, 1, 1, 4096, 0, 2e-4f);

    // fc3: Bb -> out [512,10] fp32
    LAUNCH(qfc3, 512 * 10, Bb, WF3, BF3, out, 512, 4096, 10, 2e-4f);
}

// Round 3
// 1610.693 us; speedup vs baseline: 10.7148x; 1.9196x over previous
//
#include <hip/hip_runtime.h>

#define DEV_INLINE __device__ __forceinline__

typedef int i32x4 __attribute__((ext_vector_type(4)));

// ---------------- conversion kernels ----------------

// OIHW fp32 -> [O][KK][Ipad] int8 (pad input channels with zeros)
__global__ void cvt_w_conv(const float* __restrict__ w, signed char* __restrict__ o,
                           int O, int I, int KK, int Ipad) {
    int idx = blockIdx.x * blockDim.x + threadIdx.x;
    int total = O * KK * Ipad;
    if (idx >= total) return;
    int i = idx % Ipad;
    int t = idx / Ipad;
    int kk = t % KK;
    int oc = t / KK;
    float v = (i < I) ? w[(oc * I + i) * KK + kk] : 0.0f;
    o[idx] = (signed char)(int)v;
}

// conv1 weights: OIHW [96][3][5][5] fp32 -> [96][128] int8, byte [oc][tap*4+c]
__global__ void cvt_w1(const float* __restrict__ w, signed char* __restrict__ o) {
    int idx = blockIdx.x * blockDim.x + threadIdx.x;
    if (idx >= 96 * 128) return;
    int b = idx & 127;
    int oc = idx >> 7;
    int tap = b >> 2;
    int c = b & 3;
    float v = (tap < 25 && c < 3) ? w[(oc * 3 + c) * 25 + tap] : 0.0f;
    o[idx] = (signed char)(int)v;
}

__global__ void cvt_i8(const float* __restrict__ w, signed char* __restrict__ o, int n) {
    int idx = blockIdx.x * blockDim.x + threadIdx.x;
    if (idx < n) o[idx] = (signed char)(int)w[idx];
}

__global__ void cvt_i32(const float* __restrict__ b, int* __restrict__ o, int n) {
    int idx = blockIdx.x * blockDim.x + threadIdx.x;
    if (idx < n) o[idx] = (int)b[idx];
}

// ---------------- quantize input: NCHW fp32 [512,3,32,32] -> NHWC int8 [512,32,32,4] ----------------

__global__ void quantize_in(const float* __restrict__ x, signed char* __restrict__ q, int total) {
    int idx = blockIdx.x * blockDim.x + threadIdx.x;
    if (idx >= total) return;                 // total = 512*32*32
    int hw = idx & 1023;
    int n = idx >> 10;
    const float* xp = x + n * 3072 + hw;
    int b[4];
#pragma unroll
    for (int c = 0; c < 3; ++c) {
        float v = rintf(xp[c * 1024] / 0.05f);
        v = fminf(fmaxf(v, -128.0f), 127.0f);
        b[c] = (int)v;
    }
    b[3] = 0;
    int packed = (b[0] & 0xff) | ((b[1] & 0xff) << 8) | ((b[2] & 0xff) << 16) | (b[3] << 24);
    ((int*)q)[idx] = packed;
}

// ---------------- conv1 MFMA with LDS im2col ----------------
// act: [512,32,32,4] int8 (packed ints). wq: [96][128] int8. out NHWC [M,96].
// Block: 256 thr = 4 waves; 64 sites (2 rows of one image) x 96 oc. K=128 (25 taps + pad).

__global__ void conv1_mfma(const signed char* __restrict__ act,
                           const signed char* __restrict__ wq,
                           const int* __restrict__ bias,
                           signed char* __restrict__ out) {
    __shared__ int lds[64 * 36];                  // 64 sites x 144 B (128 data + 16 pad)

    int tid = threadIdx.x;
    int lane = tid & 63;
    int wid = tid >> 6;
    int siteBase = blockIdx.x * 64;

    // ---- cooperative LDS im2col fill: thread -> (site_local = tid>>2, tap-group g = tid&3) ----
    {
        int site_local = tid >> 2;
        int g = tid & 3;
        int site = siteBase + site_local;
        int ox = site & 31;
        int oy = (site >> 5) & 31;
        int n = site >> 10;
        const int* aI = (const int*)act;
        int* dst = lds + site_local * 36 + g * 8;
#pragma unroll
        for (int j = 0; j < 8; ++j) {
            int tap = g * 8 + j;
            int v = 0;
            if (tap < 25) {
                int ky = tap / 5;
                int kx = tap - ky * 5;
                int iy = oy - 2 + ky;
                int ix = ox - 2 + kx;
                if ((unsigned)iy < 32u && (unsigned)ix < 32u)
                    v = aI[(n << 10) + (iy << 5) + ix];
            }
            dst[j] = v;
        }
    }

    int m = lane & 15;
    int q = lane >> 4;

    // ---- B-fragments (hoisted, L1-hot) ----
    i32x4 bfrag[6][2];
#pragma unroll
    for (int j = 0; j < 6; ++j)
#pragma unroll
        for (int s = 0; s < 2; ++s)
            bfrag[j][s] = *(const i32x4*)(wq + (j * 16 + m) * 128 + s * 64 + q * 16);

    i32x4 acc[6];
#pragma unroll
    for (int j = 0; j < 6; ++j) {
        int bv = bias[j * 16 + m];
        acc[j] = (i32x4){bv, bv, bv, bv};
    }

    __syncthreads();

    // ---- MFMA: 2 k-steps x 6 oc-tiles ----
#pragma unroll
    for (int s = 0; s < 2; ++s) {
        i32x4 a = *(const i32x4*)(lds + (wid * 16 + m) * 36 + s * 16 + q * 4);
#pragma unroll
        for (int j = 0; j < 6; ++j)
            acc[j] = __builtin_amdgcn_mfma_i32_16x16x64_i8(a, bfrag[j][s], acc[j], 0, 0, 0);
    }

    // ---- requant + store (same D mapping as conv_mfma: site=q*4+r, oc=m+16j) ----
#pragma unroll
    for (int j = 0; j < 6; ++j) {
        int oc = j * 16 + m;
#pragma unroll
        for (int r = 0; r < 4; ++r) {
            int site = siteBase + wid * 16 + q * 4 + r;
            float v = floorf((float)acc[j][r] * 2e-3f);
            v = fminf(fmaxf(v, 0.0f), 127.0f);
            out[(size_t)site * 96 + oc] = (signed char)v;
        }
    }
}

// ---------------- implicit-GEMM MFMA conv (also FC with KS=1) ----------------
// act: NHWC int8 (Cin multiple of 16), wq: [Cout][KS*KS*Cin] int8, out: NHWC int8
// Wave tile: 16 sites x 64 oc. Block: 4 waves -> 64 sites x 64 oc.
// grid.x = M/64 (M = N*OH*OW, multiple of 64), grid.y = Cout/64.

template <int KS, int CIN>
__global__ void conv_mfma(const signed char* __restrict__ act,
                          const signed char* __restrict__ wq,
                          const int* __restrict__ bias,
                          signed char* __restrict__ out,
                          int H, int W, int OH, int OW, int Cout, int pad, float M) {
    constexpr int C16 = CIN / 16;                 // 16-byte chunks per tap
    constexpr int K16 = KS * KS * C16;            // total 16-chunks in K
    constexpr int KSTEPS = (K16 + 3) / 4;         // 64-wide MFMA K-steps
    constexpr int KROW = KS * KS * CIN;           // weight row bytes

    int lane = threadIdx.x & 63;
    int wid = threadIdx.x >> 6;
    int siteBase = blockIdx.x * 64 + wid * 16;
    int oc0 = blockIdx.y * 64;

    int mA = lane & 15;                           // A row within tile
    int q = lane >> 4;                            // k-chunk sub-index (0..3)

    // A-side site (fixed per lane)
    int siteA = siteBase + mA;
    int ox = siteA % OW;
    int t = siteA / OW;
    int oy = t % OH;
    int n = t / OH;
    const size_t rowBase = (size_t)n * H;         // in rows

    // D-side oc (fixed per lane)
    int ocD = oc0 + (lane & 15);

    i32x4 acc[4];
#pragma unroll
    for (int j = 0; j < 4; ++j) {
        int bv = bias[ocD + 16 * j];
        acc[j] = (i32x4){bv, bv, bv, bv};
    }

    // weight chunk base per jtile: row (ocD+16j), chunk offset q*16; advances 64 B/step
    const signed char* wp[4];
#pragma unroll
    for (int j = 0; j < 4; ++j)
        wp[j] = wq + (size_t)(ocD + 16 * j) * KROW + q * 16;

    for (int step = 0; step < KSTEPS; ++step) {
        int k16 = step * 4 + q;
        int tap = k16 / C16;                      // const-div -> magic mul
        int c16 = k16 - tap * C16;
        int iy = oy - pad + tap / KS;
        int ix = ox - pad + tap % KS;
        bool kok = (k16 < K16);
        bool aok = kok && ((unsigned)iy < (unsigned)H) && ((unsigned)ix < (unsigned)W);

        i32x4 a = (i32x4){0, 0, 0, 0};
        if (aok)
            a = *(const i32x4*)(act + (((rowBase + iy) * W + ix) * CIN + c16 * 16));

#pragma unroll
        for (int j = 0; j < 4; ++j) {
            i32x4 b = (i32x4){0, 0, 0, 0};
            if (kok) b = *(const i32x4*)(wp[j] + (size_t)step * 64);
            acc[j] = __builtin_amdgcn_mfma_i32_16x16x64_i8(a, b, acc[j], 0, 0, 0);
        }
    }

    // D layout: row = (lane>>4)*4 + reg, col = lane&15 (+16j)
    int q4 = q * 4;
#pragma unroll
    for (int j = 0; j < 4; ++j) {
        int oc = ocD + 16 * j;
#pragma unroll
        for (int r = 0; r < 4; ++r) {
            int site = siteBase + q4 + r;
            float v = floorf((float)acc[j][r] * M);
            v = fminf(fmaxf(v, 0.0f), 127.0f);
            out[(size_t)site * Cout + oc] = (signed char)v;
        }
    }
}

// ---------------- maxpool 3x3 stride 2, NHWC, 4 channels per thread ----------------

__global__ void qmaxpool(const signed char* __restrict__ in, signed char* __restrict__ out,
                         int N, int H, int W, int C4, int OH, int OW) {
    int idx = blockIdx.x * blockDim.x + threadIdx.x;
    int total = N * OH * OW * C4;
    if (idx >= total) return;
    int cc = idx % C4;
    int t = idx / C4;
    int ox = t % OW; t /= OW;
    int oy = t % OH;
    int n = t / OH;
    const int* ip = (const int*)in;
    int base = ((n * H + oy * 2) * W + ox * 2) * C4 + cc;
    int m0 = -128, m1 = -128, m2 = -128, m3 = -128;
#pragma unroll
    for (int dy = 0; dy < 3; ++dy)
#pragma unroll
        for (int dx = 0; dx < 3; ++dx) {
            int v = ip[base + (dy * W + dx) * C4];
            m0 = max(m0, (int)(signed char)(v & 0xff));
            m1 = max(m1, (int)(signed char)((v >> 8) & 0xff));
            m2 = max(m2, (int)(signed char)((v >> 16) & 0xff));
            m3 = max(m3, (int)(signed char)(v >> 24));
        }
    ((int*)out)[idx] = (m0 & 0xff) | ((m1 & 0xff) << 8) | ((m2 & 0xff) << 16) | (m3 << 24);
}

// ---------------- global avg pool over 3x3 + floor: [512,3,3,256] -> [512,256] ----------------

__global__ void qgap(const signed char* __restrict__ in, signed char* __restrict__ out) {
    int idx = blockIdx.x * blockDim.x + threadIdx.x;
    if (idx >= 512 * 256) return;
    int c = idx & 255;
    int n = idx >> 8;
    const signed char* p = in + n * 9 * 256 + c;
    int s = 0;
#pragma unroll
    for (int k = 0; k < 9; ++k) s += p[k * 256];
    out[idx] = (signed char)(s / 9);   // values >= 0, so this is floor(mean)
}

// ---------------- final FC (no relu), fp32 output ----------------

DEV_INLINE int dot4(int a, int b, int c) {
#if __has_builtin(__builtin_amdgcn_sdot4)
    return __builtin_amdgcn_sdot4(a, b, c, false);
#else
    return c
        + (int)(signed char)(a)       * (int)(signed char)(b)
        + (int)(signed char)(a >> 8)  * (int)(signed char)(b >> 8)
        + (int)(signed char)(a >> 16) * (int)(signed char)(b >> 16)
        + (int)(signed char)(a >> 24) * (int)(signed char)(b >> 24);
#endif
}

__global__ void qfc3(const signed char* __restrict__ act,
                     const signed char* __restrict__ wq,
                     const int* __restrict__ bias,
                     float* __restrict__ out,
                     int B, int K, int O, float M) {
    int idx = blockIdx.x * blockDim.x + threadIdx.x;
    if (idx >= B * O) return;
    int o = idx % O;
    int b = idx / O;
    int k4 = K >> 2;
    int acc = bias[o];
    const int* aI = (const int*)act + b * k4;
    const int* wI = (const int*)wq + o * k4;
    for (int k = 0; k < k4; ++k) acc = dot4(aI[k], wI[k], acc);
    float v = floorf((float)acc * M);
    v = fminf(fmaxf(v, -128.0f), 127.0f);
    out[idx] = v;
}

// ---------------- launch ----------------

#define LAUNCH(kern, n, ...) kern<<<dim3(((n) + 255) / 256), dim3(256), 0, stream>>>(__VA_ARGS__)

extern "C" void kernel_launch(void* const* d_in, const int* in_sizes, int n_in,
                              void* d_out, int out_size, void* d_ws, size_t ws_size,
                              hipStream_t stream) {
    const float* x   = (const float*)d_in[0];
    const float* w1  = (const float*)d_in[1];
    const float* b1  = (const float*)d_in[2];
    const float* w2  = (const float*)d_in[3];
    const float* b2  = (const float*)d_in[4];
    const float* w3  = (const float*)d_in[5];
    const float* b3  = (const float*)d_in[6];
    const float* w4  = (const float*)d_in[7];
    const float* b4  = (const float*)d_in[8];
    const float* w5  = (const float*)d_in[9];
    const float* b5  = (const float*)d_in[10];
    const float* wf1 = (const float*)d_in[11];
    const float* bf1 = (const float*)d_in[12];
    const float* wf2 = (const float*)d_in[13];
    const float* bf2 = (const float*)d_in[14];
    const float* wf3 = (const float*)d_in[15];
    const float* bf3 = (const float*)d_in[16];
    float* out = (float*)d_out;

    char* ws = (char*)d_ws;
    size_t off = 0;
    auto A = [&](size_t sz) -> size_t {
        size_t o = off;
        off += (sz + 255) & ~(size_t)255;
        return o;
    };

    size_t wq1  = A(96 * 128);
    size_t wq2  = A(256 * 25 * 96);
    size_t wq3  = A(384 * 9 * 256);
    size_t wq4  = A(384 * 9 * 384);
    size_t wq5  = A(256 * 9 * 384);
    size_t wqf1 = A(4096 * 256);
    size_t wqf2 = A((size_t)4096 * 4096);
    size_t wqf3 = A(10 * 4096);
    size_t bq1  = A(96 * 4);
    size_t bq2  = A(256 * 4);
    size_t bq3  = A(384 * 4);
    size_t bq4  = A(384 * 4);
    size_t bq5  = A(256 * 4);
    size_t bqf1 = A(4096 * 4);
    size_t bqf2 = A(4096 * 4);
    size_t bqf3 = A(10 * 4);
    size_t bufA = A(11059200);   // max: pool1 out [512,15,15,96]
    size_t bufB = A(50331648);   // max: conv1 out [512,32,32,96]
    if (off > ws_size) return;   // workspace too small — bail rather than corrupt

    signed char* W1 = (signed char*)(ws + wq1);
    signed char* W2 = (signed char*)(ws + wq2);
    signed char* W3 = (signed char*)(ws + wq3);
    signed char* W4 = (signed char*)(ws + wq4);
    signed char* W5 = (signed char*)(ws + wq5);
    signed char* WF1 = (signed char*)(ws + wqf1);
    signed char* WF2 = (signed char*)(ws + wqf2);
    signed char* WF3 = (signed char*)(ws + wqf3);
    int* B1 = (int*)(ws + bq1);
    int* B2 = (int*)(ws + bq2);
    int* B3 = (int*)(ws + bq3);
    int* B4 = (int*)(ws + bq4);
    int* B5 = (int*)(ws + bq5);
    int* BF1 = (int*)(ws + bqf1);
    int* BF2 = (int*)(ws + bqf2);
    int* BF3 = (int*)(ws + bqf3);
    signed char* A_ = (signed char*)(ws + bufA);
    signed char* Bb = (signed char*)(ws + bufB);

    // ---- weight/bias conversion ----
    LAUNCH(cvt_w1, 96 * 128, w1, W1);
    LAUNCH(cvt_w_conv, 256 * 25 * 96, w2, W2, 256, 96, 25, 96);
    LAUNCH(cvt_w_conv, 384 * 9 * 256, w3, W3, 384, 256, 9, 256);
    LAUNCH(cvt_w_conv, 384 * 9 * 384, w4, W4, 384, 384, 9, 384);
    LAUNCH(cvt_w_conv, 256 * 9 * 384, w5, W5, 256, 384, 9, 384);
    LAUNCH(cvt_i8, 4096 * 256, wf1, WF1, 4096 * 256);
    LAUNCH(cvt_i8, 4096 * 4096, wf2, WF2, 4096 * 4096);
    LAUNCH(cvt_i8, 10 * 4096, wf3, WF3, 10 * 4096);
    LAUNCH(cvt_i32, 96, b1, B1, 96);
    LAUNCH(cvt_i32, 256, b2, B2, 256);
    LAUNCH(cvt_i32, 384, b3, B3, 384);
    LAUNCH(cvt_i32, 384, b4, B4, 384);
    LAUNCH(cvt_i32, 256, b5, B5, 256);
    LAUNCH(cvt_i32, 4096, bf1, BF1, 4096);
    LAUNCH(cvt_i32, 4096, bf2, BF2, 4096);
    LAUNCH(cvt_i32, 10, bf3, BF3, 10);

    // ---- forward ----
    // quantize: x -> A_ [512,32,32,4]
    LAUNCH(quantize_in, 512 * 1024, x, A_, 512 * 1024);

    // conv1 (MFMA + LDS im2col): A_ -> Bb [512,32,32,96]
    conv1_mfma<<<dim3(512 * 1024 / 64), dim3(256), 0, stream>>>(A_, W1, B1, Bb);

    // pool1: Bb -> A_ [512,15,15,96]
    LAUNCH(qmaxpool, 512 * 15 * 15 * 24, Bb, A_, 512, 32, 32, 24, 15, 15);

    // conv2 (MFMA): A_ -> Bb [512,15,15,256]; M = 512*225 = 115200
    conv_mfma<5, 96><<<dim3(115200 / 64, 256 / 64), dim3(256), 0, stream>>>(
        A_, W2, B2, Bb, 15, 15, 15, 15, 256, 2, 4e-4f);

    // pool2: Bb -> A_ [512,7,7,256]
    LAUNCH(qmaxpool, 512 * 7 * 7 * 64, Bb, A_, 512, 15, 15, 64, 7, 7);

    // conv3 (MFMA): A_ -> Bb [512,7,7,384]; M = 25088
    conv_mfma<3, 256><<<dim3(25088 / 64, 384 / 64), dim3(256), 0, stream>>>(
        A_, W3, B3, Bb, 7, 7, 7, 7, 384, 1, 2e-4f);

    // conv4 (MFMA): Bb -> A_ [512,7,7,384]
    conv_mfma<3, 384><<<dim3(25088 / 64, 384 / 64), dim3(256), 0, stream>>>(
        Bb, W4, B4, A_, 7, 7, 7, 7, 384, 1, 2e-4f);

    // conv5 (MFMA): A_ -> Bb [512,7,7,256]
    conv_mfma<3, 384><<<dim3(25088 / 64, 256 / 64), dim3(256), 0, stream>>>(
        A_, W5, B5, Bb, 7, 7, 7, 7, 256, 1, 2e-4f);

    // pool3: Bb -> A_ [512,3,3,256]
    LAUNCH(qmaxpool, 512 * 3 * 3 * 64, Bb, A_, 512, 7, 7, 64, 3, 3);

    // gap: A_ -> Bb [512,256]
    LAUNCH(qgap, 512 * 256, A_, Bb);

    // fc1 (MFMA as KS=1 conv): Bb -> A_ [512,4096]
    conv_mfma<1, 256><<<dim3(512 / 64, 4096 / 64), dim3(256), 0, stream>>>(
        Bb, WF1, BF1, A_, 1, 1, 1, 1, 4096, 0, 1e-3f);

    // fc2 (MFMA): A_ -> Bb [512,4096]
    conv_mfma<1, 4096><<<dim3(512 / 64, 4096 / 64), dim3(256), 0, stream>>>(
        A_, WF2, BF2, Bb, 1, 1, 1, 1, 4096, 0, 2e-4f);

    // fc3: Bb -> out [512,10] fp32
    LAUNCH(qfc3, 512 * 10, Bb, WF3, BF3, out, 512, 4096, 10, 2e-4f);
}

// Round 4
// 989.218 us; speedup vs baseline: 17.4464x; 1.6282x over previous
//
#include <hip/hip_runtime.h>

#define DEV_INLINE __device__ __forceinline__

typedef int i32x4 __attribute__((ext_vector_type(4)));

// ---------------- conversion kernels ----------------

// Repack weights to MFMA B-fragment-major order:
//   dst[tile][step][lane][16B]; lane = n + 16*q holds B[n=oc%16][k = step*64 + q*16 + j]
//   src layout: [O][I][KK] fp32 (OIHW convs flattened; KK=1 for FC -> [O][I])
//   k maps to (tap, c): tap = k / I (taps are k-major outer), c = k % I. Zero-fill k >= I*KK.
__global__ void cvt_w_frag(const float* __restrict__ w, signed char* __restrict__ o,
                           int O, int I, int KK, int KSTEPS) {
    int idx = blockIdx.x * blockDim.x + threadIdx.x;
    int total = (O >> 4) * KSTEPS * 1024;
    if (idx >= total) return;
    int j = idx & 15;
    int lane = (idx >> 4) & 63;
    int step = (idx >> 10) % KSTEPS;
    int tile = idx / (KSTEPS << 10);
    int oc = tile * 16 + (lane & 15);
    int k = step * 64 + (lane >> 4) * 16 + j;
    int tap = k / I;
    int c = k - tap * I;
    float v = (tap < KK) ? w[((size_t)oc * I + c) * KK + tap] : 0.0f;
    o[idx] = (signed char)(int)v;
}

// conv1 weights: OIHW [96][3][5][5] fp32 -> [96][128] int8, byte [oc][tap*4+c]
__global__ void cvt_w1(const float* __restrict__ w, signed char* __restrict__ o) {
    int idx = blockIdx.x * blockDim.x + threadIdx.x;
    if (idx >= 96 * 128) return;
    int b = idx & 127;
    int oc = idx >> 7;
    int tap = b >> 2;
    int c = b & 3;
    float v = (tap < 25 && c < 3) ? w[(oc * 3 + c) * 25 + tap] : 0.0f;
    o[idx] = (signed char)(int)v;
}

__global__ void cvt_i8(const float* __restrict__ w, signed char* __restrict__ o, int n) {
    int idx = blockIdx.x * blockDim.x + threadIdx.x;
    if (idx < n) o[idx] = (signed char)(int)w[idx];
}

__global__ void cvt_i32(const float* __restrict__ b, int* __restrict__ o, int n) {
    int idx = blockIdx.x * blockDim.x + threadIdx.x;
    if (idx < n) o[idx] = (int)b[idx];
}

// ---------------- quantize input: NCHW fp32 [512,3,32,32] -> NHWC int8 [512,32,32,4] ----------------

__global__ void quantize_in(const float* __restrict__ x, signed char* __restrict__ q, int total) {
    int idx = blockIdx.x * blockDim.x + threadIdx.x;
    if (idx >= total) return;                 // total = 512*32*32
    int hw = idx & 1023;
    int n = idx >> 10;
    const float* xp = x + n * 3072 + hw;
    int b[4];
#pragma unroll
    for (int c = 0; c < 3; ++c) {
        float v = rintf(xp[c * 1024] / 0.05f);
        v = fminf(fmaxf(v, -128.0f), 127.0f);
        b[c] = (int)v;
    }
    b[3] = 0;
    int packed = (b[0] & 0xff) | ((b[1] & 0xff) << 8) | ((b[2] & 0xff) << 16) | (b[3] << 24);
    ((int*)q)[idx] = packed;
}

// ---------------- conv1 MFMA with LDS im2col ----------------
// act: [512,32,32,4] int8 (packed ints). wq: [96][128] int8. out NHWC [M,96].
// Block: 256 thr = 4 waves; 64 sites (2 rows of one image) x 96 oc. K=128 (25 taps + pad).

__global__ void conv1_mfma(const signed char* __restrict__ act,
                           const signed char* __restrict__ wq,
                           const int* __restrict__ bias,
                           signed char* __restrict__ out) {
    __shared__ int lds[64 * 36];                  // 64 sites x 144 B (128 data + 16 pad)

    int tid = threadIdx.x;
    int lane = tid & 63;
    int wid = tid >> 6;
    int siteBase = blockIdx.x * 64;

    // ---- cooperative LDS im2col fill: thread -> (site_local = tid>>2, tap-group g = tid&3) ----
    {
        int site_local = tid >> 2;
        int g = tid & 3;
        int site = siteBase + site_local;
        int ox = site & 31;
        int oy = (site >> 5) & 31;
        int n = site >> 10;
        const int* aI = (const int*)act;
        int* dst = lds + site_local * 36 + g * 8;
#pragma unroll
        for (int j = 0; j < 8; ++j) {
            int tap = g * 8 + j;
            int v = 0;
            if (tap < 25) {
                int ky = tap / 5;
                int kx = tap - ky * 5;
                int iy = oy - 2 + ky;
                int ix = ox - 2 + kx;
                if ((unsigned)iy < 32u && (unsigned)ix < 32u)
                    v = aI[(n << 10) + (iy << 5) + ix];
            }
            dst[j] = v;
        }
    }

    int m = lane & 15;
    int q = lane >> 4;

    // ---- B-fragments (hoisted, L1-hot) ----
    i32x4 bfrag[6][2];
#pragma unroll
    for (int j = 0; j < 6; ++j)
#pragma unroll
        for (int s = 0; s < 2; ++s)
            bfrag[j][s] = *(const i32x4*)(wq + (j * 16 + m) * 128 + s * 64 + q * 16);

    i32x4 acc[6];
#pragma unroll
    for (int j = 0; j < 6; ++j) {
        int bv = bias[j * 16 + m];
        acc[j] = (i32x4){bv, bv, bv, bv};
    }

    __syncthreads();

    // ---- MFMA: 2 k-steps x 6 oc-tiles ----
#pragma unroll
    for (int s = 0; s < 2; ++s) {
        i32x4 a = *(const i32x4*)(lds + (wid * 16 + m) * 36 + s * 16 + q * 4);
#pragma unroll
        for (int j = 0; j < 6; ++j)
            acc[j] = __builtin_amdgcn_mfma_i32_16x16x64_i8(a, bfrag[j][s], acc[j], 0, 0, 0);
    }

    // ---- requant + store (site=q*4+r, oc=m+16j) ----
#pragma unroll
    for (int j = 0; j < 6; ++j) {
        int oc = j * 16 + m;
#pragma unroll
        for (int r = 0; r < 4; ++r) {
            int site = siteBase + wid * 16 + q * 4 + r;
            float v = floorf((float)acc[j][r] * 2e-3f);
            v = fminf(fmaxf(v, 0.0f), 127.0f);
            out[(size_t)site * 96 + oc] = (signed char)v;
        }
    }
}

// ---------------- implicit-GEMM MFMA conv (also FC with KS=1) ----------------
// act: NHWC int8 (Cin multiple of 16), wqf: fragment-major [Cout/16][KSTEPS][64][16] int8
// Wave tile: 16 sites x 64 oc. Block: 4 waves -> 64 sites x 64 oc.
// grid.x = M/64, grid.y = Cout/64.

template <int KS, int CIN>
__global__ void conv_mfma(const signed char* __restrict__ act,
                          const signed char* __restrict__ wqf,
                          const int* __restrict__ bias,
                          signed char* __restrict__ out,
                          int H, int W, int OH, int OW, int Cout, int pad, float M) {
    constexpr int C16 = CIN / 16;                 // 16-byte chunks per tap
    constexpr int K16 = KS * KS * C16;            // total 16-chunks in K
    constexpr int KSTEPS = (K16 + 3) / 4;         // 64-wide MFMA K-steps

    int lane = threadIdx.x & 63;
    int wid = threadIdx.x >> 6;
    int siteBase = blockIdx.x * 64 + wid * 16;
    int oc0 = blockIdx.y * 64;

    int mA = lane & 15;                           // A row within tile
    int q = lane >> 4;                            // k-chunk sub-index (0..3)

    // A-side site (fixed per lane)
    int siteA = siteBase + mA;
    int ox = siteA % OW;
    int t = siteA / OW;
    int oy = t % OH;
    int n = t / OH;
    const size_t rowBase = (size_t)n * H;         // in rows

    // D-side oc (fixed per lane)
    int ocD = oc0 + (lane & 15);

    i32x4 acc[4];
#pragma unroll
    for (int j = 0; j < 4; ++j) {
        int bv = bias[ocD + 16 * j];
        acc[j] = (i32x4){bv, bv, bv, bv};
    }

    // fragment-major weight base: tile (oc0/16 + j), fully coalesced lane*16
    const signed char* wb = wqf + ((size_t)(blockIdx.y * 4) * KSTEPS) * 1024 + lane * 16;

    for (int step = 0; step < KSTEPS; ++step) {
        int k16 = step * 4 + q;
        int tap = k16 / C16;                      // const-div -> magic mul
        int c16 = k16 - tap * C16;
        int iy = oy - pad + tap / KS;
        int ix = ox - pad + tap % KS;
        bool aok = ((unsigned)iy < (unsigned)H) && ((unsigned)ix < (unsigned)W) && (k16 < K16);

        i32x4 a = (i32x4){0, 0, 0, 0};
        if (aok)
            a = *(const i32x4*)(act + (((rowBase + iy) * W + ix) * CIN + c16 * 16));

#pragma unroll
        for (int j = 0; j < 4; ++j) {
            i32x4 b = *(const i32x4*)(wb + ((size_t)(j * KSTEPS + step)) * 1024);
            acc[j] = __builtin_amdgcn_mfma_i32_16x16x64_i8(a, b, acc[j], 0, 0, 0);
        }
    }

    // D layout: row = (lane>>4)*4 + reg, col = lane&15 (+16j)
    int q4 = q * 4;
#pragma unroll
    for (int j = 0; j < 4; ++j) {
        int oc = ocD + 16 * j;
#pragma unroll
        for (int r = 0; r < 4; ++r) {
            int site = siteBase + q4 + r;
            float v = floorf((float)acc[j][r] * M);
            v = fminf(fmaxf(v, 0.0f), 127.0f);
            out[(size_t)site * Cout + oc] = (signed char)v;
        }
    }
}

// ---------------- maxpool 3x3 stride 2, NHWC, 4 channels per thread ----------------

__global__ void qmaxpool(const signed char* __restrict__ in, signed char* __restrict__ out,
                         int N, int H, int W, int C4, int OH, int OW) {
    int idx = blockIdx.x * blockDim.x + threadIdx.x;
    int total = N * OH * OW * C4;
    if (idx >= total) return;
    int cc = idx % C4;
    int t = idx / C4;
    int ox = t % OW; t /= OW;
    int oy = t % OH;
    int n = t / OH;
    const int* ip = (const int*)in;
    int base = ((n * H + oy * 2) * W + ox * 2) * C4 + cc;
    int m0 = -128, m1 = -128, m2 = -128, m3 = -128;
#pragma unroll
    for (int dy = 0; dy < 3; ++dy)
#pragma unroll
        for (int dx = 0; dx < 3; ++dx) {
            int v = ip[base + (dy * W + dx) * C4];
            m0 = max(m0, (int)(signed char)(v & 0xff));
            m1 = max(m1, (int)(signed char)((v >> 8) & 0xff));
            m2 = max(m2, (int)(signed char)((v >> 16) & 0xff));
            m3 = max(m3, (int)(signed char)(v >> 24));
        }
    ((int*)out)[idx] = (m0 & 0xff) | ((m1 & 0xff) << 8) | ((m2 & 0xff) << 16) | (m3 << 24);
}

// ---------------- global avg pool over 3x3 + floor: [512,3,3,256] -> [512,256] ----------------

__global__ void qgap(const signed char* __restrict__ in, signed char* __restrict__ out) {
    int idx = blockIdx.x * blockDim.x + threadIdx.x;
    if (idx >= 512 * 256) return;
    int c = idx & 255;
    int n = idx >> 8;
    const signed char* p = in + n * 9 * 256 + c;
    int s = 0;
#pragma unroll
    for (int k = 0; k < 9; ++k) s += p[k * 256];
    out[idx] = (signed char)(s / 9);   // values >= 0, so this is floor(mean)
}

// ---------------- final FC (no relu), fp32 output ----------------

DEV_INLINE int dot4(int a, int b, int c) {
#if __has_builtin(__builtin_amdgcn_sdot4)
    return __builtin_amdgcn_sdot4(a, b, c, false);
#else
    return c
        + (int)(signed char)(a)       * (int)(signed char)(b)
        + (int)(signed char)(a >> 8)  * (int)(signed char)(b >> 8)
        + (int)(signed char)(a >> 16) * (int)(signed char)(b >> 16)
        + (int)(signed char)(a >> 24) * (int)(signed char)(b >> 24);
#endif
}

__global__ void qfc3(const signed char* __restrict__ act,
                     const signed char* __restrict__ wq,
                     const int* __restrict__ bias,
                     float* __restrict__ out,
                     int B, int K, int O, float M) {
    int idx = blockIdx.x * blockDim.x + threadIdx.x;
    if (idx >= B * O) return;
    int o = idx % O;
    int b = idx / O;
    int k4 = K >> 2;
    int acc = bias[o];
    const int* aI = (const int*)act + b * k4;
    const int* wI = (const int*)wq + o * k4;
    for (int k = 0; k < k4; ++k) acc = dot4(aI[k], wI[k], acc);
    float v = floorf((float)acc * M);
    v = fminf(fmaxf(v, -128.0f), 127.0f);
    out[idx] = v;
}

// ---------------- launch ----------------

#define LAUNCH(kern, n, ...) kern<<<dim3(((n) + 255) / 256), dim3(256), 0, stream>>>(__VA_ARGS__)

extern "C" void kernel_launch(void* const* d_in, const int* in_sizes, int n_in,
                              void* d_out, int out_size, void* d_ws, size_t ws_size,
                              hipStream_t stream) {
    const float* x   = (const float*)d_in[0];
    const float* w1  = (const float*)d_in[1];
    const float* b1  = (const float*)d_in[2];
    const float* w2  = (const float*)d_in[3];
    const float* b2  = (const float*)d_in[4];
    const float* w3  = (const float*)d_in[5];
    const float* b3  = (const float*)d_in[6];
    const float* w4  = (const float*)d_in[7];
    const float* b4  = (const float*)d_in[8];
    const float* w5  = (const float*)d_in[9];
    const float* b5  = (const float*)d_in[10];
    const float* wf1 = (const float*)d_in[11];
    const float* bf1 = (const float*)d_in[12];
    const float* wf2 = (const float*)d_in[13];
    const float* bf2 = (const float*)d_in[14];
    const float* wf3 = (const float*)d_in[15];
    const float* bf3 = (const float*)d_in[16];
    float* out = (float*)d_out;

    char* ws = (char*)d_ws;
    size_t off = 0;
    auto A = [&](size_t sz) -> size_t {
        size_t o = off;
        off += (sz + 255) & ~(size_t)255;
        return o;
    };

    // fragment-major sizes: (O/16)*KSTEPS*1024
    size_t wq1  = A(96 * 128);
    size_t wq2  = A((size_t)16 * 38 * 1024);      // conv2: K=2400 -> 38 steps
    size_t wq3  = A((size_t)24 * 36 * 1024);      // conv3: K=2304 -> 36
    size_t wq4  = A((size_t)24 * 54 * 1024);      // conv4: K=3456 -> 54
    size_t wq5  = A((size_t)16 * 54 * 1024);      // conv5: K=3456 -> 54
    size_t wqf1 = A((size_t)256 * 4 * 1024);      // fc1: K=256 -> 4
    size_t wqf2 = A((size_t)256 * 64 * 1024);     // fc2: K=4096 -> 64
    size_t wqf3 = A(10 * 4096);                   // fc3 stays flat
    size_t bq1  = A(96 * 4);
    size_t bq2  = A(256 * 4);
    size_t bq3  = A(384 * 4);
    size_t bq4  = A(384 * 4);
    size_t bq5  = A(256 * 4);
    size_t bqf1 = A(4096 * 4);
    size_t bqf2 = A(4096 * 4);
    size_t bqf3 = A(10 * 4);
    size_t bufA = A(11059200);   // max: pool1 out [512,15,15,96]
    size_t bufB = A(50331648);   // max: conv1 out [512,32,32,96]
    if (off > ws_size) return;   // workspace too small — bail rather than corrupt

    signed char* W1 = (signed char*)(ws + wq1);
    signed char* W2 = (signed char*)(ws + wq2);
    signed char* W3 = (signed char*)(ws + wq3);
    signed char* W4 = (signed char*)(ws + wq4);
    signed char* W5 = (signed char*)(ws + wq5);
    signed char* WF1 = (signed char*)(ws + wqf1);
    signed char* WF2 = (signed char*)(ws + wqf2);
    signed char* WF3 = (signed char*)(ws + wqf3);
    int* B1 = (int*)(ws + bq1);
    int* B2 = (int*)(ws + bq2);
    int* B3 = (int*)(ws + bq3);
    int* B4 = (int*)(ws + bq4);
    int* B5 = (int*)(ws + bq5);
    int* BF1 = (int*)(ws + bqf1);
    int* BF2 = (int*)(ws + bqf2);
    int* BF3 = (int*)(ws + bqf3);
    signed char* A_ = (signed char*)(ws + bufA);
    signed char* Bb = (signed char*)(ws + bufB);

    // ---- weight/bias conversion (fp32 -> fragment-major int8) ----
    LAUNCH(cvt_w1, 96 * 128, w1, W1);
    LAUNCH(cvt_w_frag, 16 * 38 * 1024, w2, W2, 256, 96, 25, 38);
    LAUNCH(cvt_w_frag, 24 * 36 * 1024, w3, W3, 384, 256, 9, 36);
    LAUNCH(cvt_w_frag, 24 * 54 * 1024, w4, W4, 384, 384, 9, 54);
    LAUNCH(cvt_w_frag, 16 * 54 * 1024, w5, W5, 256, 384, 9, 54);
    LAUNCH(cvt_w_frag, 256 * 4 * 1024, wf1, WF1, 4096, 256, 1, 4);
    LAUNCH(cvt_w_frag, 256 * 64 * 1024, wf2, WF2, 4096, 4096, 1, 64);
    LAUNCH(cvt_i8, 10 * 4096, wf3, WF3, 10 * 4096);
    LAUNCH(cvt_i32, 96, b1, B1, 96);
    LAUNCH(cvt_i32, 256, b2, B2, 256);
    LAUNCH(cvt_i32, 384, b3, B3, 384);
    LAUNCH(cvt_i32, 384, b4, B4, 384);
    LAUNCH(cvt_i32, 256, b5, B5, 256);
    LAUNCH(cvt_i32, 4096, bf1, BF1, 4096);
    LAUNCH(cvt_i32, 4096, bf2, BF2, 4096);
    LAUNCH(cvt_i32, 10, bf3, BF3, 10);

    // ---- forward ----
    // quantize: x -> A_ [512,32,32,4]
    LAUNCH(quantize_in, 512 * 1024, x, A_, 512 * 1024);

    // conv1 (MFMA + LDS im2col): A_ -> Bb [512,32,32,96]
    conv1_mfma<<<dim3(512 * 1024 / 64), dim3(256), 0, stream>>>(A_, W1, B1, Bb);

    // pool1: Bb -> A_ [512,15,15,96]
    LAUNCH(qmaxpool, 512 * 15 * 15 * 24, Bb, A_, 512, 32, 32, 24, 15, 15);

    // conv2 (MFMA): A_ -> Bb [512,15,15,256]; M = 115200
    conv_mfma<5, 96><<<dim3(115200 / 64, 256 / 64), dim3(256), 0, stream>>>(
        A_, W2, B2, Bb, 15, 15, 15, 15, 256, 2, 4e-4f);

    // pool2: Bb -> A_ [512,7,7,256]
    LAUNCH(qmaxpool, 512 * 7 * 7 * 64, Bb, A_, 512, 15, 15, 64, 7, 7);

    // conv3 (MFMA): A_ -> Bb [512,7,7,384]; M = 25088
    conv_mfma<3, 256><<<dim3(25088 / 64, 384 / 64), dim3(256), 0, stream>>>(
        A_, W3, B3, Bb, 7, 7, 7, 7, 384, 1, 2e-4f);

    // conv4 (MFMA): Bb -> A_ [512,7,7,384]
    conv_mfma<3, 384><<<dim3(25088 / 64, 384 / 64), dim3(256), 0, stream>>>(
        Bb, W4, B4, A_, 7, 7, 7, 7, 384, 1, 2e-4f);

    // conv5 (MFMA): A_ -> Bb [512,7,7,256]
    conv_mfma<3, 384><<<dim3(25088 / 64, 256 / 64), dim3(256), 0, stream>>>(
        A_, W5, B5, Bb, 7, 7, 7, 7, 256, 1, 2e-4f);

    // pool3: Bb -> A_ [512,3,3,256]
    LAUNCH(qmaxpool, 512 * 3 * 3 * 64, Bb, A_, 512, 7, 7, 64, 3, 3);

    // gap: A_ -> Bb [512,256]
    LAUNCH(qgap, 512 * 256, A_, Bb);

    // fc1 (MFMA as KS=1 conv): Bb -> A_ [512,4096]
    conv_mfma<1, 256><<<dim3(512 / 64, 4096 / 64), dim3(256), 0, stream>>>(
        Bb, WF1, BF1, A_, 1, 1, 1, 1, 4096, 0, 1e-3f);

    // fc2 (MFMA): A_ -> Bb [512,4096]
    conv_mfma<1, 4096><<<dim3(512 / 64, 4096 / 64), dim3(256), 0, stream>>>(
        A_, WF2, BF2, Bb, 1, 1, 1, 1, 4096, 0, 2e-4f);

    // fc3: Bb -> out [512,10] fp32
    LAUNCH(qfc3, 512 * 10, Bb, WF3, BF3, out, 512, 4096, 10, 2e-4f);
}

// Round 5
// 767.668 us; speedup vs baseline: 22.4814x; 1.2886x over previous
//
#include <hip/hip_runtime.h>

#define DEV_INLINE __device__ __forceinline__

typedef int i32x4 __attribute__((ext_vector_type(4)));
typedef int i32x16 __attribute__((ext_vector_type(16)));

DEV_INLINE int dot4(int a, int b, int c) {
#if __has_builtin(__builtin_amdgcn_sdot4)
    return __builtin_amdgcn_sdot4(a, b, c, false);
#else
    return c
        + (int)(signed char)(a)       * (int)(signed char)(b)
        + (int)(signed char)(a >> 8)  * (int)(signed char)(b >> 8)
        + (int)(signed char)(a >> 16) * (int)(signed char)(b >> 16)
        + (int)(signed char)(a >> 24) * (int)(signed char)(b >> 24);
#endif
}

// ---------------- conversion kernels ----------------

// Repack weights to 32-wide MFMA B-fragment-major order:
//   dst[tile32][step][lane][16B]; lane holds B[n = oc%32 = lane&31][k = step*32 + (lane>>5)*16 + j]
//   src layout: [O][I][KK] fp32 (OIHW convs flattened; KK=1 for FC)
//   k <-> (tap, c): tap = k / I, c = k % I (tap-major K). Zero-fill k >= I*KK.
__global__ void cvt_w_frag32(const float* __restrict__ w, signed char* __restrict__ o,
                             int O, int I, int KK, int KSTEPS) {
    int idx = blockIdx.x * blockDim.x + threadIdx.x;
    int total = (O >> 5) * KSTEPS * 1024;
    if (idx >= total) return;
    int j = idx & 15;
    int lane = (idx >> 4) & 63;
    int step = (idx >> 10) % KSTEPS;
    int tile = idx / (KSTEPS << 10);
    int oc = tile * 32 + (lane & 31);
    int k = step * 32 + ((lane >> 5) << 4) + j;
    int tap = k / I;
    int c = k - tap * I;
    float v = (tap < KK) ? w[((size_t)oc * I + c) * KK + tap] : 0.0f;
    o[idx] = (signed char)(int)v;
}

// conv1 weights: OIHW [96][3][5][5] fp32 -> [96][128] int8, byte [oc][tap*4+c]
__global__ void cvt_w1(const float* __restrict__ w, signed char* __restrict__ o) {
    int idx = blockIdx.x * blockDim.x + threadIdx.x;
    if (idx >= 96 * 128) return;
    int b = idx & 127;
    int oc = idx >> 7;
    int tap = b >> 2;
    int c = b & 3;
    float v = (tap < 25 && c < 3) ? w[(oc * 3 + c) * 25 + tap] : 0.0f;
    o[idx] = (signed char)(int)v;
}

__global__ void cvt_i8(const float* __restrict__ w, signed char* __restrict__ o, int n) {
    int idx = blockIdx.x * blockDim.x + threadIdx.x;
    if (idx < n) o[idx] = (signed char)(int)w[idx];
}

__global__ void cvt_i32(const float* __restrict__ b, int* __restrict__ o, int n) {
    int idx = blockIdx.x * blockDim.x + threadIdx.x;
    if (idx < n) o[idx] = (int)b[idx];
}

// ---------------- quantize input: NCHW fp32 [512,3,32,32] -> NHWC int8 [512,32,32,4] ----------------

__global__ void quantize_in(const float* __restrict__ x, signed char* __restrict__ q, int total) {
    int idx = blockIdx.x * blockDim.x + threadIdx.x;
    if (idx >= total) return;                 // total = 512*32*32
    int hw = idx & 1023;
    int n = idx >> 10;
    const float* xp = x + n * 3072 + hw;
    int b[4];
#pragma unroll
    for (int c = 0; c < 3; ++c) {
        float v = rintf(xp[c * 1024] / 0.05f);
        v = fminf(fmaxf(v, -128.0f), 127.0f);
        b[c] = (int)v;
    }
    b[3] = 0;
    int packed = (b[0] & 0xff) | ((b[1] & 0xff) << 8) | ((b[2] & 0xff) << 16) | (b[3] << 24);
    ((int*)q)[idx] = packed;
}

// ---------------- conv1 MFMA with LDS im2col (16x16x64 path, Cin=4) ----------------

__global__ void conv1_mfma(const signed char* __restrict__ act,
                           const signed char* __restrict__ wq,
                           const int* __restrict__ bias,
                           signed char* __restrict__ out) {
    __shared__ int lds[64 * 36];                  // 64 sites x 144 B (128 data + 16 pad)

    int tid = threadIdx.x;
    int lane = tid & 63;
    int wid = tid >> 6;
    int siteBase = blockIdx.x * 64;

    {
        int site_local = tid >> 2;
        int g = tid & 3;
        int site = siteBase + site_local;
        int ox = site & 31;
        int oy = (site >> 5) & 31;
        int n = site >> 10;
        const int* aI = (const int*)act;
        int* dst = lds + site_local * 36 + g * 8;
#pragma unroll
        for (int j = 0; j < 8; ++j) {
            int tap = g * 8 + j;
            int v = 0;
            if (tap < 25) {
                int ky = tap / 5;
                int kx = tap - ky * 5;
                int iy = oy - 2 + ky;
                int ix = ox - 2 + kx;
                if ((unsigned)iy < 32u && (unsigned)ix < 32u)
                    v = aI[(n << 10) + (iy << 5) + ix];
            }
            dst[j] = v;
        }
    }

    int m = lane & 15;
    int q = lane >> 4;

    i32x4 bfrag[6][2];
#pragma unroll
    for (int j = 0; j < 6; ++j)
#pragma unroll
        for (int s = 0; s < 2; ++s)
            bfrag[j][s] = *(const i32x4*)(wq + (j * 16 + m) * 128 + s * 64 + q * 16);

    i32x4 acc[6];
#pragma unroll
    for (int j = 0; j < 6; ++j) {
        int bv = bias[j * 16 + m];
        acc[j] = (i32x4){bv, bv, bv, bv};
    }

    __syncthreads();

#pragma unroll
    for (int s = 0; s < 2; ++s) {
        i32x4 a = *(const i32x4*)(lds + (wid * 16 + m) * 36 + s * 16 + q * 4);
#pragma unroll
        for (int j = 0; j < 6; ++j)
            acc[j] = __builtin_amdgcn_mfma_i32_16x16x64_i8(a, bfrag[j][s], acc[j], 0, 0, 0);
    }

#pragma unroll
    for (int j = 0; j < 6; ++j) {
        int oc = j * 16 + m;
#pragma unroll
        for (int r = 0; r < 4; ++r) {
            int site = siteBase + wid * 16 + q * 4 + r;
            float v = floorf((float)acc[j][r] * 2e-3f);
            v = fminf(fmaxf(v, 0.0f), 127.0f);
            out[(size_t)site * 96 + oc] = (signed char)v;
        }
    }
}

// ---------------- implicit-GEMM 32x32x32 MFMA conv (also FC) ----------------
// act: NHWC int8 (Cin multiple of 16), wqf: fragment-major [Cout/32][KSTEPS][64][16]
// Wave: SITES site-tiles of 32 x OCT oc-tiles of 32. Block: 4 waves split sites.
// grid.x = M / (128*SITES), grid.y = Cout / (OCT*32). K16 must be even (all layers).

template <int KS, int CIN, int OCT, int SITES>
__launch_bounds__(256, 2)
__global__ void conv_mfma32(const signed char* __restrict__ act,
                            const signed char* __restrict__ wqf,
                            const int* __restrict__ bias,
                            signed char* __restrict__ out,
                            int H, int W, int OH, int OW, int Cout, int pad, float M) {
    constexpr int C16 = CIN / 16;                 // 16-byte chunks per tap
    constexpr int K16 = KS * KS * C16;            // total 16-chunks in K
    constexpr int KSTEPS = K16 / 2;               // 32-wide MFMA K-steps (K16 even)
    static_assert(K16 % 2 == 0, "K16 must be even");

    int lane = threadIdx.x & 63;
    int wid = threadIdx.x >> 6;
    int m32 = lane & 31;
    int q2 = lane >> 5;                           // 0/1: k-half
    int waveBase = blockIdx.x * (SITES * 128) + wid * (SITES * 32);
    int oc0 = blockIdx.y * (OCT * 32);

    // per-site-tile coordinate decode (A-side lane site)
    int oxA[SITES], oyA[SITES];
    size_t rowBaseA[SITES];
#pragma unroll
    for (int s = 0; s < SITES; ++s) {
        int site = waveBase + s * 32 + m32;
        int ox = site % OW;
        int t = site / OW;
        oxA[s] = ox;
        oyA[s] = t % OH;
        rowBaseA[s] = (size_t)(t / OH) * H;
    }

    i32x16 acc[SITES][OCT];
#pragma unroll
    for (int j = 0; j < OCT; ++j) {
        int bv = bias[oc0 + j * 32 + m32];
#pragma unroll
        for (int s = 0; s < SITES; ++s)
#pragma unroll
            for (int r = 0; r < 16; ++r)
                acc[s][j][r] = bv;
    }

    const signed char* wb = wqf + ((size_t)(blockIdx.y * OCT) * KSTEPS) * 1024 + lane * 16;

    for (int step = 0; step < KSTEPS; ++step) {
        int k16 = step * 2 + q2;
        int tap = k16 / C16;                      // const-div -> magic mul
        int c16 = k16 - tap * C16;
        int ty = tap / KS;
        int tx = tap - ty * KS;

        i32x4 a[SITES];
#pragma unroll
        for (int s = 0; s < SITES; ++s) {
            int iy = oyA[s] - pad + ty;
            int ix = oxA[s] - pad + tx;
            bool aok = ((unsigned)iy < (unsigned)H) && ((unsigned)ix < (unsigned)W);
            a[s] = (i32x4){0, 0, 0, 0};
            if (aok)
                a[s] = *(const i32x4*)(act + (((rowBaseA[s] + iy) * W + ix) * CIN + c16 * 16));
        }

#pragma unroll
        for (int j = 0; j < OCT; ++j) {
            i32x4 b = *(const i32x4*)(wb + ((size_t)(j * KSTEPS + step)) * 1024);
#pragma unroll
            for (int s = 0; s < SITES; ++s)
                acc[s][j] = __builtin_amdgcn_mfma_i32_32x32x32_i8(a[s], b, acc[s][j], 0, 0, 0);
        }
    }

    // D layout: col(oc) = lane&31, row(site) = (r&3) + 8*(r>>2) + 4*q2
#pragma unroll
    for (int s = 0; s < SITES; ++s) {
#pragma unroll
        for (int j = 0; j < OCT; ++j) {
            int oc = oc0 + j * 32 + m32;
#pragma unroll
            for (int r = 0; r < 16; ++r) {
                int row = (r & 3) + 8 * (r >> 2) + 4 * q2;
                int site = waveBase + s * 32 + row;
                float v = floorf((float)acc[s][j][r] * M);
                v = fminf(fmaxf(v, 0.0f), 127.0f);
                out[(size_t)site * Cout + oc] = (signed char)v;
            }
        }
    }
}

// ---------------- maxpool 3x3 stride 2, NHWC, 4 channels per thread ----------------

__global__ void qmaxpool(const signed char* __restrict__ in, signed char* __restrict__ out,
                         int N, int H, int W, int C4, int OH, int OW) {
    int idx = blockIdx.x * blockDim.x + threadIdx.x;
    int total = N * OH * OW * C4;
    if (idx >= total) return;
    int cc = idx % C4;
    int t = idx / C4;
    int ox = t % OW; t /= OW;
    int oy = t % OH;
    int n = t / OH;
    const int* ip = (const int*)in;
    int base = ((n * H + oy * 2) * W + ox * 2) * C4 + cc;
    int m0 = -128, m1 = -128, m2 = -128, m3 = -128;
#pragma unroll
    for (int dy = 0; dy < 3; ++dy)
#pragma unroll
        for (int dx = 0; dx < 3; ++dx) {
            int v = ip[base + (dy * W + dx) * C4];
            m0 = max(m0, (int)(signed char)(v & 0xff));
            m1 = max(m1, (int)(signed char)((v >> 8) & 0xff));
            m2 = max(m2, (int)(signed char)((v >> 16) & 0xff));
            m3 = max(m3, (int)(signed char)(v >> 24));
        }
    ((int*)out)[idx] = (m0 & 0xff) | ((m1 & 0xff) << 8) | ((m2 & 0xff) << 16) | (m3 << 24);
}

// ---------------- global avg pool over 3x3 + floor: [512,3,3,256] -> [512,256] ----------------

__global__ void qgap(const signed char* __restrict__ in, signed char* __restrict__ out) {
    int idx = blockIdx.x * blockDim.x + threadIdx.x;
    if (idx >= 512 * 256) return;
    int c = idx & 255;
    int n = idx >> 8;
    const signed char* p = in + n * 9 * 256 + c;
    int s = 0;
#pragma unroll
    for (int k = 0; k < 9; ++k) s += p[k * 256];
    out[idx] = (signed char)(s / 9);   // values >= 0, so this is floor(mean)
}

// ---------------- final FC (no relu), fp32 out: one wave per (b,o), shuffle reduce ----------------

__global__ void qfc3_wave(const signed char* __restrict__ act,
                          const signed char* __restrict__ wq,
                          const int* __restrict__ bias,
                          float* __restrict__ out) {
    int gid = blockIdx.x * blockDim.x + threadIdx.x;
    int wave = gid >> 6;
    int lane = gid & 63;
    if (wave >= 512 * 10) return;
    int o = wave % 10;
    int b = wave / 10;
    const int* aI = (const int*)act + b * 1024;
    const int* wI = (const int*)wq + o * 1024;
    int acc = 0;
#pragma unroll
    for (int it = 0; it < 16; ++it) {
        int k = it * 64 + lane;
        acc = dot4(aI[k], wI[k], acc);
    }
#pragma unroll
    for (int s = 32; s; s >>= 1) acc += __shfl_xor(acc, s);
    if (lane == 0) {
        float v = floorf((float)(acc + bias[o]) * 2e-4f);
        v = fminf(fmaxf(v, -128.0f), 127.0f);
        out[b * 10 + o] = v;
    }
}

// ---------------- launch ----------------

#define LAUNCH(kern, n, ...) kern<<<dim3(((n) + 255) / 256), dim3(256), 0, stream>>>(__VA_ARGS__)

extern "C" void kernel_launch(void* const* d_in, const int* in_sizes, int n_in,
                              void* d_out, int out_size, void* d_ws, size_t ws_size,
                              hipStream_t stream) {
    const float* x   = (const float*)d_in[0];
    const float* w1  = (const float*)d_in[1];
    const float* b1  = (const float*)d_in[2];
    const float* w2  = (const float*)d_in[3];
    const float* b2  = (const float*)d_in[4];
    const float* w3  = (const float*)d_in[5];
    const float* b3  = (const float*)d_in[6];
    const float* w4  = (const float*)d_in[7];
    const float* b4  = (const float*)d_in[8];
    const float* w5  = (const float*)d_in[9];
    const float* b5  = (const float*)d_in[10];
    const float* wf1 = (const float*)d_in[11];
    const float* bf1 = (const float*)d_in[12];
    const float* wf2 = (const float*)d_in[13];
    const float* bf2 = (const float*)d_in[14];
    const float* wf3 = (const float*)d_in[15];
    const float* bf3 = (const float*)d_in[16];
    float* out = (float*)d_out;

    char* ws = (char*)d_ws;
    size_t off = 0;
    auto A = [&](size_t sz) -> size_t {
        size_t o = off;
        off += (sz + 255) & ~(size_t)255;
        return o;
    };

    // fragment-major sizes: (O/32)*KSTEPS*1024
    size_t wq1  = A(96 * 128);
    size_t wq2  = A((size_t)8 * 75 * 1024);       // conv2: K=2400 -> 75 steps
    size_t wq3  = A((size_t)12 * 72 * 1024);      // conv3: K=2304 -> 72
    size_t wq4  = A((size_t)12 * 108 * 1024);     // conv4: K=3456 -> 108
    size_t wq5  = A((size_t)8 * 108 * 1024);      // conv5: K=3456 -> 108
    size_t wqf1 = A((size_t)128 * 8 * 1024);      // fc1: K=256 -> 8
    size_t wqf2 = A((size_t)128 * 128 * 1024);    // fc2: K=4096 -> 128
    size_t wqf3 = A(10 * 4096);                   // fc3 flat
    size_t bq1  = A(96 * 4);
    size_t bq2  = A(256 * 4);
    size_t bq3  = A(384 * 4);
    size_t bq4  = A(384 * 4);
    size_t bq5  = A(256 * 4);
    size_t bqf1 = A(4096 * 4);
    size_t bqf2 = A(4096 * 4);
    size_t bqf3 = A(10 * 4);
    size_t bufA = A(11059200);   // max: pool1 out [512,15,15,96]
    size_t bufB = A(50331648);   // max: conv1 out [512,32,32,96]
    if (off > ws_size) return;   // workspace too small — bail rather than corrupt

    signed char* W1 = (signed char*)(ws + wq1);
    signed char* W2 = (signed char*)(ws + wq2);
    signed char* W3 = (signed char*)(ws + wq3);
    signed char* W4 = (signed char*)(ws + wq4);
    signed char* W5 = (signed char*)(ws + wq5);
    signed char* WF1 = (signed char*)(ws + wqf1);
    signed char* WF2 = (signed char*)(ws + wqf2);
    signed char* WF3 = (signed char*)(ws + wqf3);
    int* B1 = (int*)(ws + bq1);
    int* B2 = (int*)(ws + bq2);
    int* B3 = (int*)(ws + bq3);
    int* B4 = (int*)(ws + bq4);
    int* B5 = (int*)(ws + bq5);
    int* BF1 = (int*)(ws + bqf1);
    int* BF2 = (int*)(ws + bqf2);
    int* BF3 = (int*)(ws + bqf3);
    signed char* A_ = (signed char*)(ws + bufA);
    signed char* Bb = (signed char*)(ws + bufB);

    // ---- weight/bias conversion (fp32 -> fragment-major int8) ----
    LAUNCH(cvt_w1, 96 * 128, w1, W1);
    LAUNCH(cvt_w_frag32, 8 * 75 * 1024, w2, W2, 256, 96, 25, 75);
    LAUNCH(cvt_w_frag32, 12 * 72 * 1024, w3, W3, 384, 256, 9, 72);
    LAUNCH(cvt_w_frag32, 12 * 108 * 1024, w4, W4, 384, 384, 9, 108);
    LAUNCH(cvt_w_frag32, 8 * 108 * 1024, w5, W5, 256, 384, 9, 108);
    LAUNCH(cvt_w_frag32, 128 * 8 * 1024, wf1, WF1, 4096, 256, 1, 8);
    LAUNCH(cvt_w_frag32, 128 * 128 * 1024, wf2, WF2, 4096, 4096, 1, 128);
    LAUNCH(cvt_i8, 10 * 4096, wf3, WF3, 10 * 4096);
    LAUNCH(cvt_i32, 96, b1, B1, 96);
    LAUNCH(cvt_i32, 256, b2, B2, 256);
    LAUNCH(cvt_i32, 384, b3, B3, 384);
    LAUNCH(cvt_i32, 384, b4, B4, 384);
    LAUNCH(cvt_i32, 256, b5, B5, 256);
    LAUNCH(cvt_i32, 4096, bf1, BF1, 4096);
    LAUNCH(cvt_i32, 4096, bf2, BF2, 4096);
    LAUNCH(cvt_i32, 10, bf3, BF3, 10);

    // ---- forward ----
    // quantize: x -> A_ [512,32,32,4]
    LAUNCH(quantize_in, 512 * 1024, x, A_, 512 * 1024);

    // conv1 (MFMA + LDS im2col): A_ -> Bb [512,32,32,96]
    conv1_mfma<<<dim3(512 * 1024 / 64), dim3(256), 0, stream>>>(A_, W1, B1, Bb);

    // pool1: Bb -> A_ [512,15,15,96]
    LAUNCH(qmaxpool, 512 * 15 * 15 * 24, Bb, A_, 512, 32, 32, 24, 15, 15);

    // conv2: A_ -> Bb [512,15,15,256]; M = 115200 = 450*256 sites
    conv_mfma32<5, 96, 4, 2><<<dim3(450, 2), dim3(256), 0, stream>>>(
        A_, W2, B2, Bb, 15, 15, 15, 15, 256, 2, 4e-4f);

    // pool2: Bb -> A_ [512,7,7,256]
    LAUNCH(qmaxpool, 512 * 7 * 7 * 64, Bb, A_, 512, 15, 15, 64, 7, 7);

    // conv3: A_ -> Bb [512,7,7,384]; M = 25088 = 98*256
    conv_mfma32<3, 256, 3, 2><<<dim3(98, 4), dim3(256), 0, stream>>>(
        A_, W3, B3, Bb, 7, 7, 7, 7, 384, 1, 2e-4f);

    // conv4: Bb -> A_ [512,7,7,384]
    conv_mfma32<3, 384, 3, 2><<<dim3(98, 4), dim3(256), 0, stream>>>(
        Bb, W4, B4, A_, 7, 7, 7, 7, 384, 1, 2e-4f);

    // conv5: A_ -> Bb [512,7,7,256]
    conv_mfma32<3, 384, 2, 2><<<dim3(98, 4), dim3(256), 0, stream>>>(
        A_, W5, B5, Bb, 7, 7, 7, 7, 256, 1, 2e-4f);

    // pool3: Bb -> A_ [512,3,3,256]
    LAUNCH(qmaxpool, 512 * 3 * 3 * 64, Bb, A_, 512, 7, 7, 64, 3, 3);

    // gap: A_ -> Bb [512,256]
    LAUNCH(qgap, 512 * 256, A_, Bb);

    // fc1: Bb -> A_ [512,4096]; M=512 = 4*128
    conv_mfma32<1, 256, 2, 1><<<dim3(4, 64), dim3(256), 0, stream>>>(
        Bb, WF1, BF1, A_, 1, 1, 1, 1, 4096, 0, 1e-3f);

    // fc2: A_ -> Bb [512,4096]
    conv_mfma32<1, 4096, 2, 1><<<dim3(4, 64), dim3(256), 0, stream>>>(
        A_, WF2, BF2, Bb, 1, 1, 1, 1, 4096, 0, 2e-4f);

    // fc3: Bb -> out [512,10] fp32; one wave per output
    qfc3_wave<<<dim3(512 * 10 * 64 / 256), dim3(256), 0, stream>>>(Bb, WF3, BF3, out);
}

// Round 6
// 679.405 us; speedup vs baseline: 25.4020x; 1.1299x over previous
//
#include <hip/hip_runtime.h>

#define DEV_INLINE __device__ __forceinline__

typedef int i32x4 __attribute__((ext_vector_type(4)));
typedef int i32x16 __attribute__((ext_vector_type(16)));

DEV_INLINE int dot4(int a, int b, int c) {
#if __has_builtin(__builtin_amdgcn_sdot4)
    return __builtin_amdgcn_sdot4(a, b, c, false);
#else
    return c
        + (int)(signed char)(a)       * (int)(signed char)(b)
        + (int)(signed char)(a >> 8)  * (int)(signed char)(b >> 8)
        + (int)(signed char)(a >> 16) * (int)(signed char)(b >> 16)
        + (int)(signed char)(a >> 24) * (int)(signed char)(b >> 24);
#endif
}

// ---------------- conversion kernels ----------------

// Repack weights to 32-wide MFMA B-fragment-major order, K reordered tap-major:
//   step = tap*CP + cpair;  lane holds B[n = oc%32][element c = cpair*32 + (lane>>5)*16 + j of tap]
//   src layout: [O][I][KK] fp32 (OIHW convs flattened; KK=1 for FC). CP = I/32.
__global__ void cvt_w_frag32(const float* __restrict__ w, signed char* __restrict__ o,
                             int O, int I, int KK, int CP, int KSTEPS) {
    int idx = blockIdx.x * blockDim.x + threadIdx.x;
    int total = (O >> 5) * KSTEPS * 1024;
    if (idx >= total) return;
    int j = idx & 15;
    int lane = (idx >> 4) & 63;
    int step = (idx >> 10) % KSTEPS;
    int tile = idx / (KSTEPS << 10);
    int oc = tile * 32 + (lane & 31);
    int tap = step / CP;
    int cpair = step - tap * CP;
    int c = cpair * 32 + ((lane >> 5) << 4) + j;
    float v = w[((size_t)oc * I + c) * KK + tap];
    o[idx] = (signed char)(int)v;
}

// conv1 weights: OIHW [96][3][5][5] fp32 -> [96][128] int8, byte [oc][tap*4+c]
__global__ void cvt_w1(const float* __restrict__ w, signed char* __restrict__ o) {
    int idx = blockIdx.x * blockDim.x + threadIdx.x;
    if (idx >= 96 * 128) return;
    int b = idx & 127;
    int oc = idx >> 7;
    int tap = b >> 2;
    int c = b & 3;
    float v = (tap < 25 && c < 3) ? w[(oc * 3 + c) * 25 + tap] : 0.0f;
    o[idx] = (signed char)(int)v;
}

__global__ void cvt_i8(const float* __restrict__ w, signed char* __restrict__ o, int n) {
    int idx = blockIdx.x * blockDim.x + threadIdx.x;
    if (idx < n) o[idx] = (signed char)(int)w[idx];
}

__global__ void cvt_i32(const float* __restrict__ b, int* __restrict__ o, int n) {
    int idx = blockIdx.x * blockDim.x + threadIdx.x;
    if (idx < n) o[idx] = (int)b[idx];
}

// ---------------- quantize input: NCHW fp32 [512,3,32,32] -> NHWC int8 [512,32,32,4] ----------------

__global__ void quantize_in(const float* __restrict__ x, signed char* __restrict__ q, int total) {
    int idx = blockIdx.x * blockDim.x + threadIdx.x;
    if (idx >= total) return;                 // total = 512*32*32
    int hw = idx & 1023;
    int n = idx >> 10;
    const float* xp = x + n * 3072 + hw;
    int b[4];
#pragma unroll
    for (int c = 0; c < 3; ++c) {
        float v = rintf(xp[c * 1024] / 0.05f);
        v = fminf(fmaxf(v, -128.0f), 127.0f);
        b[c] = (int)v;
    }
    b[3] = 0;
    int packed = (b[0] & 0xff) | ((b[1] & 0xff) << 8) | ((b[2] & 0xff) << 16) | (b[3] << 24);
    ((int*)q)[idx] = packed;
}

// ---------------- conv1 MFMA with LDS im2col (16x16x64 path, Cin=4) ----------------

__global__ void conv1_mfma(const signed char* __restrict__ act,
                           const signed char* __restrict__ wq,
                           const int* __restrict__ bias,
                           signed char* __restrict__ out) {
    __shared__ int lds[64 * 36];                  // 64 sites x 144 B (128 data + 16 pad)

    int tid = threadIdx.x;
    int lane = tid & 63;
    int wid = tid >> 6;
    int siteBase = blockIdx.x * 64;

    {
        int site_local = tid >> 2;
        int g = tid & 3;
        int site = siteBase + site_local;
        int ox = site & 31;
        int oy = (site >> 5) & 31;
        int n = site >> 10;
        const int* aI = (const int*)act;
        int* dst = lds + site_local * 36 + g * 8;
#pragma unroll
        for (int j = 0; j < 8; ++j) {
            int tap = g * 8 + j;
            int v = 0;
            if (tap < 25) {
                int ky = tap / 5;
                int kx = tap - ky * 5;
                int iy = oy - 2 + ky;
                int ix = ox - 2 + kx;
                if ((unsigned)iy < 32u && (unsigned)ix < 32u)
                    v = aI[(n << 10) + (iy << 5) + ix];
            }
            dst[j] = v;
        }
    }

    int m = lane & 15;
    int q = lane >> 4;

    i32x4 bfrag[6][2];
#pragma unroll
    for (int j = 0; j < 6; ++j)
#pragma unroll
        for (int s = 0; s < 2; ++s)
            bfrag[j][s] = *(const i32x4*)(wq + (j * 16 + m) * 128 + s * 64 + q * 16);

    i32x4 acc[6];
#pragma unroll
    for (int j = 0; j < 6; ++j) {
        int bv = bias[j * 16 + m];
        acc[j] = (i32x4){bv, bv, bv, bv};
    }

    __syncthreads();

#pragma unroll
    for (int s = 0; s < 2; ++s) {
        i32x4 a = *(const i32x4*)(lds + (wid * 16 + m) * 36 + s * 16 + q * 4);
#pragma unroll
        for (int j = 0; j < 6; ++j)
            acc[j] = __builtin_amdgcn_mfma_i32_16x16x64_i8(a, bfrag[j][s], acc[j], 0, 0, 0);
    }

#pragma unroll
    for (int j = 0; j < 6; ++j) {
        int oc = j * 16 + m;
#pragma unroll
        for (int r = 0; r < 4; ++r) {
            int site = siteBase + wid * 16 + q * 4 + r;
            float v = floorf((float)acc[j][r] * 2e-3f);
            v = fminf(fmaxf(v, 0.0f), 127.0f);
            out[(size_t)site * 96 + oc] = (signed char)v;
        }
    }
}

// ---------------- implicit-GEMM 32x32x32 MFMA conv (also FC) ----------------
// act: NHWC int8 (Cin multiple of 32), wqf: fragment-major [Cout/32][KSTEPS][64][16],
// K ordered tap-major (step = tap*CP + cpair). Wave: SITES site-tiles x OCT oc-tiles.
// grid.x = M / (128*SITES), grid.y = Cout / (OCT*32).

template <int KS, int CIN, int OCT, int SITES>
__launch_bounds__(256, 2)
__global__ void conv_mfma32(const signed char* __restrict__ act,
                            const signed char* __restrict__ wqf,
                            const int* __restrict__ bias,
                            signed char* __restrict__ out,
                            int H, int W, int OH, int OW, int Cout, int pad, float M) {
    constexpr int C16 = CIN / 16;
    constexpr int CP = C16 / 2;                   // k-steps per tap
    constexpr int KSTEPS = KS * KS * CP;
    static_assert(C16 % 2 == 0, "CIN must be multiple of 32");

    int lane = threadIdx.x & 63;
    int wid = threadIdx.x >> 6;
    int m32 = lane & 31;
    int q2 = lane >> 5;                           // 0/1: k-half
    int waveBase = blockIdx.x * (SITES * 128) + wid * (SITES * 32);
    int oc0 = blockIdx.y * (OCT * 32);

    // per-site-tile coordinate decode (A-side lane site)
    int oxA[SITES], oyA[SITES];
    size_t rowBaseA[SITES];
#pragma unroll
    for (int s = 0; s < SITES; ++s) {
        int site = waveBase + s * 32 + m32;
        int ox = site % OW;
        int t = site / OW;
        oxA[s] = ox;
        oyA[s] = t % OH;
        rowBaseA[s] = (size_t)(t / OH) * H;
    }

    i32x16 acc[SITES][OCT];
#pragma unroll
    for (int j = 0; j < OCT; ++j) {
        int bv = bias[oc0 + j * 32 + m32];
#pragma unroll
        for (int s = 0; s < SITES; ++s)
#pragma unroll
            for (int r = 0; r < 16; ++r)
                acc[s][j][r] = bv;
    }

    const signed char* wb = wqf + ((size_t)(blockIdx.y * OCT) * KSTEPS) * 1024 + lane * 16;
    const signed char* actq = act + q2 * 16;

#pragma unroll
    for (int tap = 0; tap < KS * KS; ++tap) {
        int ty = tap / KS;
        int tx = tap - ty * KS;

        const signed char* ap[SITES];
        bool aok[SITES];
#pragma unroll
        for (int s = 0; s < SITES; ++s) {
            int iy = oyA[s] - pad + ty;
            int ix = oxA[s] - pad + tx;
            if constexpr (KS == 1) {
                aok[s] = true;
            } else {
                aok[s] = ((unsigned)iy < (unsigned)H) && ((unsigned)ix < (unsigned)W);
            }
            ap[s] = actq + ((rowBaseA[s] + iy) * W + ix) * CIN;
        }
        const signed char* wt = wb + (size_t)tap * CP * 1024;

#pragma unroll
        for (int cp = 0; cp < CP; ++cp) {
            i32x4 a[SITES];
#pragma unroll
            for (int s = 0; s < SITES; ++s) {
                a[s] = (i32x4){0, 0, 0, 0};
                if (aok[s]) a[s] = *(const i32x4*)(ap[s] + cp * 32);
            }
#pragma unroll
            for (int j = 0; j < OCT; ++j) {
                i32x4 b = *(const i32x4*)(wt + ((size_t)j * KSTEPS + cp) * 1024);
#pragma unroll
                for (int s = 0; s < SITES; ++s)
                    acc[s][j] = __builtin_amdgcn_mfma_i32_32x32x32_i8(a[s], b, acc[s][j], 0, 0, 0);
            }
        }
    }

    // D layout: col(oc) = lane&31, row(site) = (r&3) + 8*(r>>2) + 4*q2
#pragma unroll
    for (int s = 0; s < SITES; ++s) {
#pragma unroll
        for (int j = 0; j < OCT; ++j) {
            int oc = oc0 + j * 32 + m32;
#pragma unroll
            for (int r = 0; r < 16; ++r) {
                int row = (r & 3) + 8 * (r >> 2) + 4 * q2;
                int site = waveBase + s * 32 + row;
                float v = floorf((float)acc[s][j][r] * M);
                v = fminf(fmaxf(v, 0.0f), 127.0f);
                out[(size_t)site * Cout + oc] = (signed char)v;
            }
        }
    }
}

// ---------------- maxpool 3x3 stride 2, NHWC, 4 channels per thread ----------------

__global__ void qmaxpool(const signed char* __restrict__ in, signed char* __restrict__ out,
                         int N, int H, int W, int C4, int OH, int OW) {
    int idx = blockIdx.x * blockDim.x + threadIdx.x;
    int total = N * OH * OW * C4;
    if (idx >= total) return;
    int cc = idx % C4;
    int t = idx / C4;
    int ox = t % OW; t /= OW;
    int oy = t % OH;
    int n = t / OH;
    const int* ip = (const int*)in;
    int base = ((n * H + oy * 2) * W + ox * 2) * C4 + cc;
    int m0 = -128, m1 = -128, m2 = -128, m3 = -128;
#pragma unroll
    for (int dy = 0; dy < 3; ++dy)
#pragma unroll
        for (int dx = 0; dx < 3; ++dx) {
            int v = ip[base + (dy * W + dx) * C4];
            m0 = max(m0, (int)(signed char)(v & 0xff));
            m1 = max(m1, (int)(signed char)((v >> 8) & 0xff));
            m2 = max(m2, (int)(signed char)((v >> 16) & 0xff));
            m3 = max(m3, (int)(signed char)(v >> 24));
        }
    ((int*)out)[idx] = (m0 & 0xff) | ((m1 & 0xff) << 8) | ((m2 & 0xff) << 16) | (m3 << 24);
}

// ---------------- global avg pool over 3x3 + floor: [512,3,3,256] -> [512,256] ----------------

__global__ void qgap(const signed char* __restrict__ in, signed char* __restrict__ out) {
    int idx = blockIdx.x * blockDim.x + threadIdx.x;
    if (idx >= 512 * 256) return;
    int c = idx & 255;
    int n = idx >> 8;
    const signed char* p = in + n * 9 * 256 + c;
    int s = 0;
#pragma unroll
    for (int k = 0; k < 9; ++k) s += p[k * 256];
    out[idx] = (signed char)(s / 9);   // values >= 0, so this is floor(mean)
}

// ---------------- final FC (no relu), fp32 out: one wave per (b,o), shuffle reduce ----------------

__global__ void qfc3_wave(const signed char* __restrict__ act,
                          const signed char* __restrict__ wq,
                          const int* __restrict__ bias,
                          float* __restrict__ out) {
    int gid = blockIdx.x * blockDim.x + threadIdx.x;
    int wave = gid >> 6;
    int lane = gid & 63;
    if (wave >= 512 * 10) return;
    int o = wave % 10;
    int b = wave / 10;
    const int* aI = (const int*)act + b * 1024;
    const int* wI = (const int*)wq + o * 1024;
    int acc = 0;
#pragma unroll
    for (int it = 0; it < 16; ++it) {
        int k = it * 64 + lane;
        acc = dot4(aI[k], wI[k], acc);
    }
#pragma unroll
    for (int s = 32; s; s >>= 1) acc += __shfl_xor(acc, s);
    if (lane == 0) {
        float v = floorf((float)(acc + bias[o]) * 2e-4f);
        v = fminf(fmaxf(v, -128.0f), 127.0f);
        out[b * 10 + o] = v;
    }
}

// ---------------- launch ----------------

#define LAUNCH(kern, n, ...) kern<<<dim3(((n) + 255) / 256), dim3(256), 0, stream>>>(__VA_ARGS__)

extern "C" void kernel_launch(void* const* d_in, const int* in_sizes, int n_in,
                              void* d_out, int out_size, void* d_ws, size_t ws_size,
                              hipStream_t stream) {
    const float* x   = (const float*)d_in[0];
    const float* w1  = (const float*)d_in[1];
    const float* b1  = (const float*)d_in[2];
    const float* w2  = (const float*)d_in[3];
    const float* b2  = (const float*)d_in[4];
    const float* w3  = (const float*)d_in[5];
    const float* b3  = (const float*)d_in[6];
    const float* w4  = (const float*)d_in[7];
    const float* b4  = (const float*)d_in[8];
    const float* w5  = (const float*)d_in[9];
    const float* b5  = (const float*)d_in[10];
    const float* wf1 = (const float*)d_in[11];
    const float* bf1 = (const float*)d_in[12];
    const float* wf2 = (const float*)d_in[13];
    const float* bf2 = (const float*)d_in[14];
    const float* wf3 = (const float*)d_in[15];
    const float* bf3 = (const float*)d_in[16];
    float* out = (float*)d_out;

    char* ws = (char*)d_ws;
    size_t off = 0;
    auto A = [&](size_t sz) -> size_t {
        size_t o = off;
        off += (sz + 255) & ~(size_t)255;
        return o;
    };

    // fragment-major sizes: (O/32)*KSTEPS*1024
    size_t wq1  = A(96 * 128);
    size_t wq2  = A((size_t)8 * 75 * 1024);       // conv2: 25 taps x CP3
    size_t wq3  = A((size_t)12 * 72 * 1024);      // conv3: 9 x CP8
    size_t wq4  = A((size_t)12 * 108 * 1024);     // conv4: 9 x CP12
    size_t wq5  = A((size_t)8 * 108 * 1024);      // conv5: 9 x CP12
    size_t wqf1 = A((size_t)128 * 8 * 1024);      // fc1: CP8
    size_t wqf2 = A((size_t)128 * 128 * 1024);    // fc2: CP128
    size_t wqf3 = A(10 * 4096);                   // fc3 flat
    size_t bq1  = A(96 * 4);
    size_t bq2  = A(256 * 4);
    size_t bq3  = A(384 * 4);
    size_t bq4  = A(384 * 4);
    size_t bq5  = A(256 * 4);
    size_t bqf1 = A(4096 * 4);
    size_t bqf2 = A(4096 * 4);
    size_t bqf3 = A(10 * 4);
    size_t bufA = A(11059200);   // max: pool1 out [512,15,15,96]
    size_t bufB = A(50331648);   // max: conv1 out [512,32,32,96]
    if (off > ws_size) return;   // workspace too small — bail rather than corrupt

    signed char* W1 = (signed char*)(ws + wq1);
    signed char* W2 = (signed char*)(ws + wq2);
    signed char* W3 = (signed char*)(ws + wq3);
    signed char* W4 = (signed char*)(ws + wq4);
    signed char* W5 = (signed char*)(ws + wq5);
    signed char* WF1 = (signed char*)(ws + wqf1);
    signed char* WF2 = (signed char*)(ws + wqf2);
    signed char* WF3 = (signed char*)(ws + wqf3);
    int* B1 = (int*)(ws + bq1);
    int* B2 = (int*)(ws + bq2);
    int* B3 = (int*)(ws + bq3);
    int* B4 = (int*)(ws + bq4);
    int* B5 = (int*)(ws + bq5);
    int* BF1 = (int*)(ws + bqf1);
    int* BF2 = (int*)(ws + bqf2);
    int* BF3 = (int*)(ws + bqf3);
    signed char* A_ = (signed char*)(ws + bufA);
    signed char* Bb = (signed char*)(ws + bufB);

    // ---- weight/bias conversion (fp32 -> fragment-major int8, tap-major K) ----
    LAUNCH(cvt_w1, 96 * 128, w1, W1);
    LAUNCH(cvt_w_frag32, 8 * 75 * 1024, w2, W2, 256, 96, 25, 3, 75);
    LAUNCH(cvt_w_frag32, 12 * 72 * 1024, w3, W3, 384, 256, 9, 8, 72);
    LAUNCH(cvt_w_frag32, 12 * 108 * 1024, w4, W4, 384, 384, 9, 12, 108);
    LAUNCH(cvt_w_frag32, 8 * 108 * 1024, w5, W5, 256, 384, 9, 12, 108);
    LAUNCH(cvt_w_frag32, 128 * 8 * 1024, wf1, WF1, 4096, 256, 1, 8, 8);
    LAUNCH(cvt_w_frag32, 128 * 128 * 1024, wf2, WF2, 4096, 4096, 1, 128, 128);
    LAUNCH(cvt_i8, 10 * 4096, wf3, WF3, 10 * 4096);
    LAUNCH(cvt_i32, 96, b1, B1, 96);
    LAUNCH(cvt_i32, 256, b2, B2, 256);
    LAUNCH(cvt_i32, 384, b3, B3, 384);
    LAUNCH(cvt_i32, 384, b4, B4, 384);
    LAUNCH(cvt_i32, 256, b5, B5, 256);
    LAUNCH(cvt_i32, 4096, bf1, BF1, 4096);
    LAUNCH(cvt_i32, 4096, bf2, BF2, 4096);
    LAUNCH(cvt_i32, 10, bf3, BF3, 10);

    // ---- forward ----
    // quantize: x -> A_ [512,32,32,4]
    LAUNCH(quantize_in, 512 * 1024, x, A_, 512 * 1024);

    // conv1 (MFMA + LDS im2col): A_ -> Bb [512,32,32,96]
    conv1_mfma<<<dim3(512 * 1024 / 64), dim3(256), 0, stream>>>(A_, W1, B1, Bb);

    // pool1: Bb -> A_ [512,15,15,96]
    LAUNCH(qmaxpool, 512 * 15 * 15 * 24, Bb, A_, 512, 32, 32, 24, 15, 15);

    // conv2: A_ -> Bb [512,15,15,256]; M = 115200 = 450*256 sites
    conv_mfma32<5, 96, 4, 2><<<dim3(450, 2), dim3(256), 0, stream>>>(
        A_, W2, B2, Bb, 15, 15, 15, 15, 256, 2, 4e-4f);

    // pool2: Bb -> A_ [512,7,7,256]
    LAUNCH(qmaxpool, 512 * 7 * 7 * 64, Bb, A_, 512, 15, 15, 64, 7, 7);

    // conv3: A_ -> Bb [512,7,7,384]; M = 25088 = 98*256
    conv_mfma32<3, 256, 3, 2><<<dim3(98, 4), dim3(256), 0, stream>>>(
        A_, W3, B3, Bb, 7, 7, 7, 7, 384, 1, 2e-4f);

    // conv4: Bb -> A_ [512,7,7,384]
    conv_mfma32<3, 384, 3, 2><<<dim3(98, 4), dim3(256), 0, stream>>>(
        Bb, W4, B4, A_, 7, 7, 7, 7, 384, 1, 2e-4f);

    // conv5: A_ -> Bb [512,7,7,256]
    conv_mfma32<3, 384, 2, 2><<<dim3(98, 4), dim3(256), 0, stream>>>(
        A_, W5, B5, Bb, 7, 7, 7, 7, 256, 1, 2e-4f);

    // pool3: Bb -> A_ [512,3,3,256]
    LAUNCH(qmaxpool, 512 * 3 * 3 * 64, Bb, A_, 512, 7, 7, 64, 3, 3);

    // gap: A_ -> Bb [512,256]
    LAUNCH(qgap, 512 * 256, A_, Bb);

    // fc1: Bb -> A_ [512,4096]; M=512 = 4*128
    conv_mfma32<1, 256, 2, 1><<<dim3(4, 64), dim3(256), 0, stream>>>(
        Bb, WF1, BF1, A_, 1, 1, 1, 1, 4096, 0, 1e-3f);

    // fc2: A_ -> Bb [512,4096]
    conv_mfma32<1, 4096, 2, 1><<<dim3(4, 64), dim3(256), 0, stream>>>(
        A_, WF2, BF2, Bb, 1, 1, 1, 1, 4096, 0, 2e-4f);

    // fc3: Bb -> out [512,10] fp32; one wave per output
    qfc3_wave<<<dim3(512 * 10 * 64 / 256), dim3(256), 0, stream>>>(Bb, WF3, BF3, out);
}

// Round 7
// 588.075 us; speedup vs baseline: 29.3470x; 1.1553x over previous
//
#include <hip/hip_runtime.h>

#define DEV_INLINE __device__ __forceinline__

typedef int i32x4 __attribute__((ext_vector_type(4)));
typedef int i32x16 __attribute__((ext_vector_type(16)));

DEV_INLINE int dot4(int a, int b, int c) {
#if __has_builtin(__builtin_amdgcn_sdot4)
    return __builtin_amdgcn_sdot4(a, b, c, false);
#else
    return c
        + (int)(signed char)(a)       * (int)(signed char)(b)
        + (int)(signed char)(a >> 8)  * (int)(signed char)(b >> 8)
        + (int)(signed char)(a >> 16) * (int)(signed char)(b >> 16)
        + (int)(signed char)(a >> 24) * (int)(signed char)(b >> 24);
#endif
}

typedef __attribute__((address_space(1))) const unsigned int guint;
typedef __attribute__((address_space(3))) unsigned int luint;

// async 16B/lane global->LDS DMA: lane i's 16B from g+lane*16 lands at l+lane*16
DEV_INLINE void async_cp16(const signed char* g, signed char* l) {
    __builtin_amdgcn_global_load_lds((guint*)g, (luint*)l, 16, 0, 0);
}

// ---------------- conversion kernels ----------------

// Repack weights to 32-wide MFMA B-fragment-major order, K reordered tap-major:
//   step = tap*CP + cpair;  lane holds B[n = oc%32][element c = cpair*32 + (lane>>5)*16 + j of tap]
//   src layout: [O][I][KK] fp32 (OIHW convs flattened; KK=1 for FC). CP = I/32.
__global__ void cvt_w_frag32(const float* __restrict__ w, signed char* __restrict__ o,
                             int O, int I, int KK, int CP, int KSTEPS) {
    int idx = blockIdx.x * blockDim.x + threadIdx.x;
    int total = (O >> 5) * KSTEPS * 1024;
    if (idx >= total) return;
    int j = idx & 15;
    int lane = (idx >> 4) & 63;
    int step = (idx >> 10) % KSTEPS;
    int tile = idx / (KSTEPS << 10);
    int oc = tile * 32 + (lane & 31);
    int tap = step / CP;
    int cpair = step - tap * CP;
    int c = cpair * 32 + ((lane >> 5) << 4) + j;
    float v = w[((size_t)oc * I + c) * KK + tap];
    o[idx] = (signed char)(int)v;
}

// conv1 weights: OIHW [96][3][5][5] fp32 -> [96][128] int8, byte [oc][tap*4+c]
__global__ void cvt_w1(const float* __restrict__ w, signed char* __restrict__ o) {
    int idx = blockIdx.x * blockDim.x + threadIdx.x;
    if (idx >= 96 * 128) return;
    int b = idx & 127;
    int oc = idx >> 7;
    int tap = b >> 2;
    int c = b & 3;
    float v = (tap < 25 && c < 3) ? w[(oc * 3 + c) * 25 + tap] : 0.0f;
    o[idx] = (signed char)(int)v;
}

__global__ void cvt_i8(const float* __restrict__ w, signed char* __restrict__ o, int n) {
    int idx = blockIdx.x * blockDim.x + threadIdx.x;
    if (idx < n) o[idx] = (signed char)(int)w[idx];
}

__global__ void cvt_i32(const float* __restrict__ b, int* __restrict__ o, int n) {
    int idx = blockIdx.x * blockDim.x + threadIdx.x;
    if (idx < n) o[idx] = (int)b[idx];
}

// ---------------- quantize input: NCHW fp32 [512,3,32,32] -> NHWC int8 [512,32,32,4] ----------------

__global__ void quantize_in(const float* __restrict__ x, signed char* __restrict__ q, int total) {
    int idx = blockIdx.x * blockDim.x + threadIdx.x;
    if (idx >= total) return;                 // total = 512*32*32
    int hw = idx & 1023;
    int n = idx >> 10;
    const float* xp = x + n * 3072 + hw;
    int b[4];
#pragma unroll
    for (int c = 0; c < 3; ++c) {
        float v = rintf(xp[c * 1024] / 0.05f);
        v = fminf(fmaxf(v, -128.0f), 127.0f);
        b[c] = (int)v;
    }
    b[3] = 0;
    int packed = (b[0] & 0xff) | ((b[1] & 0xff) << 8) | ((b[2] & 0xff) << 16) | (b[3] << 24);
    ((int*)q)[idx] = packed;
}

// ---------------- conv1 MFMA with LDS im2col (16x16x64 path, Cin=4) ----------------

__global__ void conv1_mfma(const signed char* __restrict__ act,
                           const signed char* __restrict__ wq,
                           const int* __restrict__ bias,
                           signed char* __restrict__ out) {
    __shared__ int lds[64 * 36];                  // 64 sites x 144 B (128 data + 16 pad)

    int tid = threadIdx.x;
    int lane = tid & 63;
    int wid = tid >> 6;
    int siteBase = blockIdx.x * 64;

    {
        int site_local = tid >> 2;
        int g = tid & 3;
        int site = siteBase + site_local;
        int ox = site & 31;
        int oy = (site >> 5) & 31;
        int n = site >> 10;
        const int* aI = (const int*)act;
        int* dst = lds + site_local * 36 + g * 8;
#pragma unroll
        for (int j = 0; j < 8; ++j) {
            int tap = g * 8 + j;
            int v = 0;
            if (tap < 25) {
                int ky = tap / 5;
                int kx = tap - ky * 5;
                int iy = oy - 2 + ky;
                int ix = ox - 2 + kx;
                if ((unsigned)iy < 32u && (unsigned)ix < 32u)
                    v = aI[(n << 10) + (iy << 5) + ix];
            }
            dst[j] = v;
        }
    }

    int m = lane & 15;
    int q = lane >> 4;

    i32x4 bfrag[6][2];
#pragma unroll
    for (int j = 0; j < 6; ++j)
#pragma unroll
        for (int s = 0; s < 2; ++s)
            bfrag[j][s] = *(const i32x4*)(wq + (j * 16 + m) * 128 + s * 64 + q * 16);

    i32x4 acc[6];
#pragma unroll
    for (int j = 0; j < 6; ++j) {
        int bv = bias[j * 16 + m];
        acc[j] = (i32x4){bv, bv, bv, bv};
    }

    __syncthreads();

#pragma unroll
    for (int s = 0; s < 2; ++s) {
        i32x4 a = *(const i32x4*)(lds + (wid * 16 + m) * 36 + s * 16 + q * 4);
#pragma unroll
        for (int j = 0; j < 6; ++j)
            acc[j] = __builtin_amdgcn_mfma_i32_16x16x64_i8(a, bfrag[j][s], acc[j], 0, 0, 0);
    }

#pragma unroll
    for (int j = 0; j < 6; ++j) {
        int oc = j * 16 + m;
#pragma unroll
        for (int r = 0; r < 4; ++r) {
            int site = siteBase + wid * 16 + q * 4 + r;
            float v = floorf((float)acc[j][r] * 2e-3f);
            v = fminf(fmaxf(v, 0.0f), 127.0f);
            out[(size_t)site * 96 + oc] = (signed char)v;
        }
    }
}

// ---------------- implicit-GEMM 32x32x32 MFMA conv (also FC), LDS-staged B ----------------
// act: NHWC int8 (Cin multiple of 32), wqf: fragment-major [Cout/32][KSTEPS][64][16],
// K tap-major (step = tap*CP + cpair). Wave: SITES site-tiles x OCT oc-tiles; block = 4 waves
// sharing the oc range -> B staged once per block in LDS (double-buffered, async DMA).
// Groups: conv -> one tap per group (GSTEP = CP); FC -> GSTEP steps per group.
// grid.x = M / (128*SITES), grid.y = Cout / (OCT*32).

template <int KS, int CIN, int OCT, int SITES, int GSTEP>
__launch_bounds__(256, 2)
__global__ void conv_mfma32(const signed char* __restrict__ act,
                            const signed char* __restrict__ wqf,
                            const int* __restrict__ bias,
                            signed char* __restrict__ out,
                            int H, int W, int OH, int OW, int Cout, int pad, float M) {
    constexpr int CP = CIN / 32;
    constexpr int KSTEPS = KS * KS * CP;
    constexpr int NG = KSTEPS / GSTEP;
    constexpr int CHUNK = OCT * GSTEP * 1024;
    static_assert(CIN % 32 == 0, "CIN must be multiple of 32");
    static_assert(KS == 1 || GSTEP == CP, "conv groups must be one tap");
    static_assert(KSTEPS % GSTEP == 0, "GSTEP must divide KSTEPS");
    static_assert((OCT * GSTEP) % 4 == 0, "stage units must split across 4 waves");

    __shared__ signed char lds[2 * CHUNK];

    int lane = threadIdx.x & 63;
    int wid = threadIdx.x >> 6;
    int m32 = lane & 31;
    int q2 = lane >> 5;                           // 0/1: k-half
    int waveBase = blockIdx.x * (SITES * 128) + wid * (SITES * 32);
    int oc0 = blockIdx.y * (OCT * 32);

    // per-site-tile coordinate decode (A-side lane site)
    int oxA[SITES], oyA[SITES];
    size_t rowBaseA[SITES];
#pragma unroll
    for (int s = 0; s < SITES; ++s) {
        int site = waveBase + s * 32 + m32;
        int ox = site % OW;
        int t = site / OW;
        oxA[s] = ox;
        oyA[s] = t % OH;
        rowBaseA[s] = (size_t)(t / OH) * H;
    }

    i32x16 acc[SITES][OCT];
#pragma unroll
    for (int j = 0; j < OCT; ++j) {
        int bv = bias[oc0 + j * 32 + m32];
#pragma unroll
        for (int s = 0; s < SITES; ++s)
#pragma unroll
            for (int r = 0; r < 16; ++r)
                acc[s][j][r] = bv;
    }

    const signed char* wblk = wqf + (size_t)(blockIdx.y * OCT) * KSTEPS * 1024;
    const signed char* actq = act + q2 * 16;

    // async-stage group g's B fragments into buffer `buf`
    auto stage = [&](int buf, int g) {
#pragma unroll
        for (int t = 0; t < (OCT * GSTEP) / 4; ++t) {
            int u = t * 4 + wid;                  // 1KB unit: u = j*GSTEP + s
            int j = u / GSTEP;
            int s = u - j * GSTEP;
            const signed char* gsrc =
                wblk + (((size_t)(j * KSTEPS + g * GSTEP + s)) << 10) + lane * 16;
            async_cp16(gsrc, lds + buf * CHUNK + (u << 10));
        }
    };

    stage(0, 0);

    for (int g = 0; g < NG; ++g) {
        __syncthreads();                          // drains DMA of buf[g&1]; prior reads of other buf done
        if (g + 1 < NG) stage((g + 1) & 1, g + 1);

        // A base pointers for this group (wave-uniform tap)
        const signed char* ap[SITES];
        bool aok[SITES];
        int ty, tx;
        if constexpr (KS == 1) { ty = 0; tx = 0; }
        else { ty = g / KS; tx = g - ty * KS; }
#pragma unroll
        for (int s = 0; s < SITES; ++s) {
            int iy = oyA[s] - pad + ty;
            int ix = oxA[s] - pad + tx;
            if constexpr (KS == 1) aok[s] = true;
            else aok[s] = ((unsigned)iy < (unsigned)H) && ((unsigned)ix < (unsigned)W);
            const signed char* p = actq + ((rowBaseA[s] + iy) * W + ix) * CIN;
            if constexpr (KS == 1) p += (size_t)g * GSTEP * 32;
            ap[s] = p;
        }

        const signed char* lb = lds + (g & 1) * CHUNK + lane * 16;
#pragma unroll
        for (int cp = 0; cp < GSTEP; ++cp) {
            i32x4 a[SITES];
#pragma unroll
            for (int s = 0; s < SITES; ++s) {
                a[s] = (i32x4){0, 0, 0, 0};
                if (aok[s]) a[s] = *(const i32x4*)(ap[s] + cp * 32);
            }
#pragma unroll
            for (int j = 0; j < OCT; ++j) {
                i32x4 b = *(const i32x4*)(lb + ((j * GSTEP + cp) << 10));
#pragma unroll
                for (int s = 0; s < SITES; ++s)
                    acc[s][j] = __builtin_amdgcn_mfma_i32_32x32x32_i8(a[s], b, acc[s][j], 0, 0, 0);
            }
        }
    }

    // D layout: col(oc) = lane&31, row(site) = (r&3) + 8*(r>>2) + 4*q2
#pragma unroll
    for (int s = 0; s < SITES; ++s) {
#pragma unroll
        for (int j = 0; j < OCT; ++j) {
            int oc = oc0 + j * 32 + m32;
#pragma unroll
            for (int r = 0; r < 16; ++r) {
                int row = (r & 3) + 8 * (r >> 2) + 4 * q2;
                int site = waveBase + s * 32 + row;
                float v = floorf((float)acc[s][j][r] * M);
                v = fminf(fmaxf(v, 0.0f), 127.0f);
                out[(size_t)site * Cout + oc] = (signed char)v;
            }
        }
    }
}

// ---------------- maxpool 3x3 stride 2, NHWC, 4 channels per thread ----------------

__global__ void qmaxpool(const signed char* __restrict__ in, signed char* __restrict__ out,
                         int N, int H, int W, int C4, int OH, int OW) {
    int idx = blockIdx.x * blockDim.x + threadIdx.x;
    int total = N * OH * OW * C4;
    if (idx >= total) return;
    int cc = idx % C4;
    int t = idx / C4;
    int ox = t % OW; t /= OW;
    int oy = t % OH;
    int n = t / OH;
    const int* ip = (const int*)in;
    int base = ((n * H + oy * 2) * W + ox * 2) * C4 + cc;
    int m0 = -128, m1 = -128, m2 = -128, m3 = -128;
#pragma unroll
    for (int dy = 0; dy < 3; ++dy)
#pragma unroll
        for (int dx = 0; dx < 3; ++dx) {
            int v = ip[base + (dy * W + dx) * C4];
            m0 = max(m0, (int)(signed char)(v & 0xff));
            m1 = max(m1, (int)(signed char)((v >> 8) & 0xff));
            m2 = max(m2, (int)(signed char)((v >> 16) & 0xff));
            m3 = max(m3, (int)(signed char)(v >> 24));
        }
    ((int*)out)[idx] = (m0 & 0xff) | ((m1 & 0xff) << 8) | ((m2 & 0xff) << 16) | (m3 << 24);
}

// ---------------- global avg pool over 3x3 + floor: [512,3,3,256] -> [512,256] ----------------

__global__ void qgap(const signed char* __restrict__ in, signed char* __restrict__ out) {
    int idx = blockIdx.x * blockDim.x + threadIdx.x;
    if (idx >= 512 * 256) return;
    int c = idx & 255;
    int n = idx >> 8;
    const signed char* p = in + n * 9 * 256 + c;
    int s = 0;
#pragma unroll
    for (int k = 0; k < 9; ++k) s += p[k * 256];
    out[idx] = (signed char)(s / 9);   // values >= 0, so this is floor(mean)
}

// ---------------- final FC (no relu), fp32 out: one wave per (b,o), shuffle reduce ----------------

__global__ void qfc3_wave(const signed char* __restrict__ act,
                          const signed char* __restrict__ wq,
                          const int* __restrict__ bias,
                          float* __restrict__ out) {
    int gid = blockIdx.x * blockDim.x + threadIdx.x;
    int wave = gid >> 6;
    int lane = gid & 63;
    if (wave >= 512 * 10) return;
    int o = wave % 10;
    int b = wave / 10;
    const int* aI = (const int*)act + b * 1024;
    const int* wI = (const int*)wq + o * 1024;
    int acc = 0;
#pragma unroll
    for (int it = 0; it < 16; ++it) {
        int k = it * 64 + lane;
        acc = dot4(aI[k], wI[k], acc);
    }
#pragma unroll
    for (int s = 32; s; s >>= 1) acc += __shfl_xor(acc, s);
    if (lane == 0) {
        float v = floorf((float)(acc + bias[o]) * 2e-4f);
        v = fminf(fmaxf(v, -128.0f), 127.0f);
        out[b * 10 + o] = v;
    }
}

// ---------------- launch ----------------

#define LAUNCH(kern, n, ...) kern<<<dim3(((n) + 255) / 256), dim3(256), 0, stream>>>(__VA_ARGS__)

extern "C" void kernel_launch(void* const* d_in, const int* in_sizes, int n_in,
                              void* d_out, int out_size, void* d_ws, size_t ws_size,
                              hipStream_t stream) {
    const float* x   = (const float*)d_in[0];
    const float* w1  = (const float*)d_in[1];
    const float* b1  = (const float*)d_in[2];
    const float* w2  = (const float*)d_in[3];
    const float* b2  = (const float*)d_in[4];
    const float* w3  = (const float*)d_in[5];
    const float* b3  = (const float*)d_in[6];
    const float* w4  = (const float*)d_in[7];
    const float* b4  = (const float*)d_in[8];
    const float* w5  = (const float*)d_in[9];
    const float* b5  = (const float*)d_in[10];
    const float* wf1 = (const float*)d_in[11];
    const float* bf1 = (const float*)d_in[12];
    const float* wf2 = (const float*)d_in[13];
    const float* bf2 = (const float*)d_in[14];
    const float* wf3 = (const float*)d_in[15];
    const float* bf3 = (const float*)d_in[16];
    float* out = (float*)d_out;

    char* ws = (char*)d_ws;
    size_t off = 0;
    auto A = [&](size_t sz) -> size_t {
        size_t o = off;
        off += (sz + 255) & ~(size_t)255;
        return o;
    };

    // fragment-major sizes: (O/32)*KSTEPS*1024
    size_t wq1  = A(96 * 128);
    size_t wq2  = A((size_t)8 * 75 * 1024);       // conv2: 25 taps x CP3
    size_t wq3  = A((size_t)12 * 72 * 1024);      // conv3: 9 x CP8
    size_t wq4  = A((size_t)12 * 108 * 1024);     // conv4: 9 x CP12
    size_t wq5  = A((size_t)8 * 108 * 1024);      // conv5: 9 x CP12
    size_t wqf1 = A((size_t)128 * 8 * 1024);      // fc1: CP8
    size_t wqf2 = A((size_t)128 * 128 * 1024);    // fc2: CP128
    size_t wqf3 = A(10 * 4096);                   // fc3 flat
    size_t bq1  = A(96 * 4);
    size_t bq2  = A(256 * 4);
    size_t bq3  = A(384 * 4);
    size_t bq4  = A(384 * 4);
    size_t bq5  = A(256 * 4);
    size_t bqf1 = A(4096 * 4);
    size_t bqf2 = A(4096 * 4);
    size_t bqf3 = A(10 * 4);
    size_t bufA = A(11059200);   // max: pool1 out [512,15,15,96]
    size_t bufB = A(50331648);   // max: conv1 out [512,32,32,96]
    if (off > ws_size) return;   // workspace too small — bail rather than corrupt

    signed char* W1 = (signed char*)(ws + wq1);
    signed char* W2 = (signed char*)(ws + wq2);
    signed char* W3 = (signed char*)(ws + wq3);
    signed char* W4 = (signed char*)(ws + wq4);
    signed char* W5 = (signed char*)(ws + wq5);
    signed char* WF1 = (signed char*)(ws + wqf1);
    signed char* WF2 = (signed char*)(ws + wqf2);
    signed char* WF3 = (signed char*)(ws + wqf3);
    int* B1 = (int*)(ws + bq1);
    int* B2 = (int*)(ws + bq2);
    int* B3 = (int*)(ws + bq3);
    int* B4 = (int*)(ws + bq4);
    int* B5 = (int*)(ws + bq5);
    int* BF1 = (int*)(ws + bqf1);
    int* BF2 = (int*)(ws + bqf2);
    int* BF3 = (int*)(ws + bqf3);
    signed char* A_ = (signed char*)(ws + bufA);
    signed char* Bb = (signed char*)(ws + bufB);

    // ---- weight/bias conversion (fp32 -> fragment-major int8, tap-major K) ----
    LAUNCH(cvt_w1, 96 * 128, w1, W1);
    LAUNCH(cvt_w_frag32, 8 * 75 * 1024, w2, W2, 256, 96, 25, 3, 75);
    LAUNCH(cvt_w_frag32, 12 * 72 * 1024, w3, W3, 384, 256, 9, 8, 72);
    LAUNCH(cvt_w_frag32, 12 * 108 * 1024, w4, W4, 384, 384, 9, 12, 108);
    LAUNCH(cvt_w_frag32, 8 * 108 * 1024, w5, W5, 256, 384, 9, 12, 108);
    LAUNCH(cvt_w_frag32, 128 * 8 * 1024, wf1, WF1, 4096, 256, 1, 8, 8);
    LAUNCH(cvt_w_frag32, 128 * 128 * 1024, wf2, WF2, 4096, 4096, 1, 128, 128);
    LAUNCH(cvt_i8, 10 * 4096, wf3, WF3, 10 * 4096);
    LAUNCH(cvt_i32, 96, b1, B1, 96);
    LAUNCH(cvt_i32, 256, b2, B2, 256);
    LAUNCH(cvt_i32, 384, b3, B3, 384);
    LAUNCH(cvt_i32, 384, b4, B4, 384);
    LAUNCH(cvt_i32, 256, b5, B5, 256);
    LAUNCH(cvt_i32, 4096, bf1, BF1, 4096);
    LAUNCH(cvt_i32, 4096, bf2, BF2, 4096);
    LAUNCH(cvt_i32, 10, bf3, BF3, 10);

    // ---- forward ----
    // quantize: x -> A_ [512,32,32,4]
    LAUNCH(quantize_in, 512 * 1024, x, A_, 512 * 1024);

    // conv1 (MFMA + LDS im2col): A_ -> Bb [512,32,32,96]
    conv1_mfma<<<dim3(512 * 1024 / 64), dim3(256), 0, stream>>>(A_, W1, B1, Bb);

    // pool1: Bb -> A_ [512,15,15,96]
    LAUNCH(qmaxpool, 512 * 15 * 15 * 24, Bb, A_, 512, 32, 32, 24, 15, 15);

    // conv2: A_ -> Bb [512,15,15,256]; M = 115200 = 450*256 sites; LDS 24 KB
    conv_mfma32<5, 96, 4, 2, 3><<<dim3(450, 2), dim3(256), 0, stream>>>(
        A_, W2, B2, Bb, 15, 15, 15, 15, 256, 2, 4e-4f);

    // pool2: Bb -> A_ [512,7,7,256]
    LAUNCH(qmaxpool, 512 * 7 * 7 * 64, Bb, A_, 512, 15, 15, 64, 7, 7);

    // conv3: A_ -> Bb [512,7,7,384]; LDS 48 KB
    conv_mfma32<3, 256, 3, 2, 8><<<dim3(98, 4), dim3(256), 0, stream>>>(
        A_, W3, B3, Bb, 7, 7, 7, 7, 384, 1, 2e-4f);

    // conv4: Bb -> A_ [512,7,7,384]; LDS 72 KB
    conv_mfma32<3, 384, 3, 2, 12><<<dim3(98, 4), dim3(256), 0, stream>>>(
        Bb, W4, B4, A_, 7, 7, 7, 7, 384, 1, 2e-4f);

    // conv5: A_ -> Bb [512,7,7,256]; LDS 48 KB
    conv_mfma32<3, 384, 2, 2, 12><<<dim3(98, 4), dim3(256), 0, stream>>>(
        A_, W5, B5, Bb, 7, 7, 7, 7, 256, 1, 2e-4f);

    // pool3: Bb -> A_ [512,3,3,256]
    LAUNCH(qmaxpool, 512 * 3 * 3 * 64, Bb, A_, 512, 7, 7, 64, 3, 3);

    // gap: A_ -> Bb [512,256]
    LAUNCH(qgap, 512 * 256, A_, Bb);

    // fc1: Bb -> A_ [512,4096]; single group (NG=1)
    conv_mfma32<1, 256, 2, 1, 8><<<dim3(4, 64), dim3(256), 0, stream>>>(
        Bb, WF1, BF1, A_, 1, 1, 1, 1, 4096, 0, 1e-3f);

    // fc2: A_ -> Bb [512,4096]; 16 groups of 8 steps (no giant unroll, no spill)
    conv_mfma32<1, 4096, 2, 1, 8><<<dim3(4, 64), dim3(256), 0, stream>>>(
        A_, WF2, BF2, Bb, 1, 1, 1, 1, 4096, 0, 2e-4f);

    // fc3: Bb -> out [512,10] fp32; one wave per output
    qfc3_wave<<<dim3(512 * 10 * 64 / 256), dim3(256), 0, stream>>>(Bb, WF3, BF3, out);
}